// Round 18
// baseline (695.580 us; speedup 1.0000x reference)
//
#include <hip/hip_runtime.h>
#include <hip/hip_bf16.h>

#define N_LAYERS 50
#define N_RES 32
#define N_SKIP 512
#define N_FEAT 8
#define BATCH 8
#define T_IN 8192
#define OUT_LEN 3077
#define NCOL (BATCH * OUT_LEN)   // 24616
#define N_TILES ((NCOL + 127) / 128)   // 193

typedef __bf16 bf16x8 __attribute__((ext_vector_type(8)));
typedef float  f32x4  __attribute__((ext_vector_type(4)));

// ---------------- workspace layout (bytes) ----------------
#define SZ_HP    ((size_t)BATCH * T_IN * 32 * 2)            // 4 MB per plane
#define OFF_HAH  ((size_t)0)
#define OFF_HAL  (OFF_HAH + SZ_HP)
#define OFF_HBH  (OFF_HAL + SZ_HP)
#define OFF_HBL  (OFF_HBH + SZ_HP)
#define OFF_WGH  (OFF_HBL + SZ_HP)                          // wg hi bf16 [50][64][64]
#define SZ_WG    ((size_t)50 * 64 * 64 * 2)
#define OFF_WGL  (OFF_WGH + SZ_WG)
#define OFF_WRH  (OFF_WGL + SZ_WG)                          // wr hi bf16 [50][32][32]
#define SZ_WR    ((size_t)50 * 32 * 32 * 2)
#define OFF_WRL  (OFF_WRH + SZ_WR)
#define OFF_BG   (OFF_WRL + SZ_WR)                          // bgate f32 [50][64]
#define SZ_BG    ((size_t)50 * 64 * 4)
#define OFF_AP   (OFF_BG + SZ_BG)                           // Apack bf16 [512][1600]
#define SZ_AP    ((size_t)512 * 1600 * 2)
#define OFF_W1P  (OFF_AP + SZ_AP)                           // w1pack bf16 [512][512]
#define SZ_W1P   ((size_t)512 * 512 * 2)
#define OFF_BS   (OFF_W1P + SZ_W1P)                         // bsum f32 [512]
#define SZ_BS    ((size_t)2048)
#define OFF_SB   (OFF_BS + SZ_BS)                           // Sb bf16 [NCOL][512] (elu applied)
#define SZ_SB    ((size_t)NCOL * 512 * 2)
#define OFF_GT   (OFF_SB + SZ_SB)                           // Gt bf16 [NCOL][1600]
#define SZ_GT    ((size_t)NCOL * 1600 * 2)

__device__ __forceinline__ float eluf(float v) {
    return v > 0.0f ? v : (__expf(v) - 1.0f);
}
__device__ __forceinline__ unsigned short f2bf_bits(float f) {
    __hip_bfloat16 h = __float2bfloat16(f);
    return *(unsigned short*)&h;
}
__device__ __forceinline__ float bfb2f(unsigned short u) {
    return __uint_as_float((unsigned)u << 16);
}

// ---------------- input 1x1 conv -> h0 hi/lo planes [b][t][32] ----------------
__global__ __launch_bounds__(256) void in_conv_kernel(
    const float* __restrict__ x, const float* __restrict__ w_in,
    const float* __restrict__ b_in,
    __hip_bfloat16* __restrict__ h_hi, __hip_bfloat16* __restrict__ h_lo)
{
    int tid = threadIdx.x;
    int t = blockIdx.x * 32 + (tid >> 3);
    int grp = tid & 7;
    int b = blockIdx.y;
    const float* xp = x + ((size_t)b * T_IN + t) * 8;
    float4 v0 = *(const float4*)xp;
    float4 v1 = *(const float4*)(xp + 4);
    float xv[8] = {v0.x, v0.y, v0.z, v0.w, v1.x, v1.y, v1.z, v1.w};
    ushort4 oh, ol;
    unsigned short hb[4], lb[4];
#pragma unroll
    for (int e = 0; e < 4; ++e) {
        int oc = grp * 4 + e;
        float acc = b_in[oc];
#pragma unroll
        for (int f = 0; f < 8; ++f) acc += w_in[oc * 8 + f] * xv[f];
        hb[e] = f2bf_bits(acc);
        lb[e] = f2bf_bits(acc - bfb2f(hb[e]));
    }
    oh.x = hb[0]; oh.y = hb[1]; oh.z = hb[2]; oh.w = hb[3];
    ol.x = lb[0]; ol.y = lb[1]; ol.z = lb[2]; ol.w = lb[3];
    size_t base = ((size_t)b * T_IN + t) * 32 + grp * 4;
    *(ushort4*)(h_hi + base) = oh;
    *(ushort4*)(h_lo + base) = ol;
}

// ---------------- pack weights (hi/lo where needed) ----------------
__global__ __launch_bounds__(256) void pack_kernel(
    const float* __restrict__ w_skip, const float* __restrict__ b_skip,
    const float* __restrict__ w_post1,
    const float* __restrict__ w_sig, const float* __restrict__ w_tanh,
    const float* __restrict__ w_res,
    const float* __restrict__ b_sig, const float* __restrict__ b_tanh,
    __hip_bfloat16* __restrict__ Apack, __hip_bfloat16* __restrict__ w1pack,
    __hip_bfloat16* __restrict__ wg_hi, __hip_bfloat16* __restrict__ wg_lo,
    __hip_bfloat16* __restrict__ wr_hi, __hip_bfloat16* __restrict__ wr_lo,
    float* __restrict__ bgate, float* __restrict__ bsum)
{
    int tid = blockIdx.x * 256 + threadIdx.x;    // 0 .. 819199
    {   // Apack[m][i*32+c] = bf16(w_skip[i][m][c])
        int m = tid / 1600;
        int r = tid - m * 1600;
        int i = r >> 5, c = r & 31;
        Apack[tid] = __float2bfloat16(w_skip[((size_t)i * 512 + m) * 32 + c]);
    }
    if (tid < 512 * 512) w1pack[tid] = __float2bfloat16(w_post1[tid]);
    if (tid < 50 * 64 * 64) {     // wg[l][row=2c+f][k=tap*32+ci]
        int l = tid >> 12;
        int rem = tid & 4095;
        int row = rem >> 6, k = rem & 63;
        int c = row >> 1, f = row & 1;
        int tap = k >> 5, ci = k & 31;
        const float* src = f ? w_tanh : w_sig;
        float v = src[(((size_t)l * 32 + c) * 32 + ci) * 2 + tap];
        unsigned short h = f2bf_bits(v);
        wg_hi[tid] = __float2bfloat16(v);
        wg_lo[tid] = __float2bfloat16(v - bfb2f(h));
    }
    if (tid < 50 * 1024) {
        float v = w_res[tid];
        unsigned short h = f2bf_bits(v);
        wr_hi[tid] = __float2bfloat16(v);
        wr_lo[tid] = __float2bfloat16(v - bfb2f(h));
    }
    if (tid < 50 * 64) {
        int l = tid >> 6, row = tid & 63;
        bgate[tid] = (row & 1) ? b_tanh[l * 32 + (row >> 1)] : b_sig[l * 32 + (row >> 1)];
    }
    if (tid < 512) {
        float s = 0.0f;
        for (int l = 0; l < N_LAYERS; ++l) s += b_skip[l * 512 + tid];
        bsum[tid] = s;
    }
}

// ---------------- 5 fused dilated layers, LDS-resident (R17 base) ----------------
// R18: staging lane remap (row = tid&127) — the old row=tid>>1 mapping put
// lanes 1/4, 3/6, ... on the same bank (1.42M SQ_LDS_BANK_CONFLICT, all from
// staging stores). Consecutive lanes -> consecutive rows: only free 2-way alias.
template <int S>
__global__ __launch_bounds__(256, 4) void group_kernel(
    const __hip_bfloat16* __restrict__ hi_in, const __hip_bfloat16* __restrict__ lo_in,
    __hip_bfloat16* __restrict__ hi_out, __hip_bfloat16* __restrict__ lo_out,
    __hip_bfloat16* __restrict__ Gt,
    const __hip_bfloat16* __restrict__ wg_hi_all, const __hip_bfloat16* __restrict__ wg_lo_all,
    const __hip_bfloat16* __restrict__ wr_hi_all, const __hip_bfloat16* __restrict__ wr_lo_all,
    const float* __restrict__ bg_all, const float* __restrict__ br_all,
    int l0, int L_in, int n_ut)
{
    __shared__ __align__(16) char lds[4][128 * 80];   // {hiA, loA, hiB, loB}
    const int tid = threadIdx.x;
    const int lane = tid & 63;
    const int wave = tid >> 6;
    const int q = lane >> 4, r = lane & 15;
    const int c0 = wave * 32;

    int bid = blockIdx.x;
    int u_t = bid % n_ut;
    int rest = bid / n_ut;
    int p = rest % S;
    int b = rest / S;
    int u0 = u_t * 96;
    int u_last = (L_in - 1 - p) / S;

    // identity A-frags for residual injection: aI[i][m=r][k=8q+j] = (k == r+16i)
    bf16x8 aI[2];
    {
        union { bf16x8 v; unsigned short u[8]; } t0, t1;
#pragma unroll
        for (int e = 0; e < 8; ++e) { t0.u[e] = 0; t1.u[e] = 0; }
        int j0 = r - 8 * q;
        int j1 = r + 16 - 8 * q;
        if (j0 >= 0 && j0 < 8) t0.u[j0] = 0x3F80;
        if (j1 >= 0 && j1 < 8) t1.u[j1] = 0x3F80;
        aI[0] = t0.v; aI[1] = t1.v;
    }

    // ---- prefetch layer-0 ks=0 gate weights (in flight during staging) ----
    bf16x8 pfh[4], pfl[4];
#pragma unroll
    for (int i = 0; i < 4; ++i) {
        int off = (16 * i + r) * 64 + q * 8;
        pfh[i] = *(const bf16x8*)(wg_hi_all + (size_t)l0 * 4096 + off);
        pfl[i] = *(const bf16x8*)(wg_lo_all + (size_t)l0 * 4096 + off);
    }

    // ---- stage input tile: rows u0..u0+127 (clamped); lane-linear rows ----
    {
        int row = tid & 127, seg = tid >> 7;
        int u = u0 + row; if (u > u_last) u = u_last;
        size_t gb = ((size_t)b * L_in + (size_t)u * S + p) * 32 + seg * 16;
        int lb = row * 80 + seg * 32;
        uint4 a0 = *(const uint4*)(hi_in + gb);
        uint4 a1 = *(const uint4*)(hi_in + gb + 8);
        uint4 c0v = *(const uint4*)(lo_in + gb);
        uint4 c1v = *(const uint4*)(lo_in + gb + 8);
        *(uint4*)(lds[0] + lb) = a0; *(uint4*)(lds[0] + lb + 16) = a1;
        *(uint4*)(lds[1] + lb) = c0v; *(uint4*)(lds[1] + lb + 16) = c1v;
    }
    __syncthreads();

    bf16x8 gstash[5][2];   // deferred Gt payloads (registers; loop unrolled)

    int cur = 0;
#pragma unroll
    for (int l = 0; l < 5; ++l) {
        const int d = 1 << l;
        const int lg = l0 + l;
        const int L_out = L_in - S * ((2 << l) - 1);
        const int v_out = 129 - (2 << l);
        const char* xh = lds[cur];
        const char* xl = lds[cur + 1];
        char* yh = lds[2 - cur];
        char* yl = lds[3 - cur];

        const __hip_bfloat16* wg_hi = wg_hi_all + (size_t)lg * 4096;
        const __hip_bfloat16* wg_lo = wg_lo_all + (size_t)lg * 4096;
        float4 bgv[4];
#pragma unroll
        for (int i = 0; i < 4; ++i) bgv[i] = *(const float4*)(bg_all + lg * 64 + 16 * i + 4 * q);

        // ---- gate GEMM: ks=0 uses prefetched frags; ks=1 loads inline ----
        f32x4 acc[4][2] = {};
#pragma unroll
        for (int ks = 0; ks < 2; ++ks) {
            bf16x8 afh[4], afl[4];
            if (ks == 0) {
#pragma unroll
                for (int i = 0; i < 4; ++i) { afh[i] = pfh[i]; afl[i] = pfl[i]; }
            } else {
#pragma unroll
                for (int i = 0; i < 4; ++i) {
                    int off = (16 * i + r) * 64 + 32 + q * 8;
                    afh[i] = *(const bf16x8*)(wg_hi + off);
                    afl[i] = *(const bf16x8*)(wg_lo + off);
                }
            }
#pragma unroll
            for (int jj = 0; jj < 2; ++jj) {
                int cn = c0 + 16 * jj + r;
                int rowk = cn;
                if (ks) { rowk = cn + d; if (rowk > 127) rowk = 127; }
                bf16x8 bhi = *(const bf16x8*)(xh + rowk * 80 + q * 16);
                bf16x8 blo = *(const bf16x8*)(xl + rowk * 80 + q * 16);
#pragma unroll
                for (int i = 0; i < 4; ++i) {
                    acc[i][jj] = __builtin_amdgcn_mfma_f32_16x16x32_bf16(afh[i], bhi, acc[i][jj], 0, 0, 0);
                    acc[i][jj] = __builtin_amdgcn_mfma_f32_16x16x32_bf16(afh[i], blo, acc[i][jj], 0, 0, 0);
                    acc[i][jj] = __builtin_amdgcn_mfma_f32_16x16x32_bf16(afl[i], bhi, acc[i][jj], 0, 0, 0);
                }
            }
        }

        // ---- gates -> yh (hi only; own cols; within-wave, no barrier) ----
#pragma unroll
        for (int i = 0; i < 4; ++i) {
#pragma unroll
            for (int jj = 0; jj < 2; ++jj) {
                int cn = c0 + 16 * jj + r;
                float ps0 = acc[i][jj][0] + bgv[i].x;
                float pt0 = acc[i][jj][1] + bgv[i].y;
                float ps1 = acc[i][jj][2] + bgv[i].z;
                float pt1 = acc[i][jj][3] + bgv[i].w;
                float g0 = __builtin_amdgcn_rcpf(1.0f + __expf(-ps0)) *
                           (1.0f - 2.0f * __builtin_amdgcn_rcpf(__expf(2.0f * pt0) + 1.0f));
                float g1 = __builtin_amdgcn_rcpf(1.0f + __expf(-ps1)) *
                           (1.0f - 2.0f * __builtin_amdgcn_rcpf(__expf(2.0f * pt1) + 1.0f));
                *(unsigned int*)(yh + cn * 80 + 16 * i + 4 * q) =
                    (unsigned)f2bf_bits(g0) | ((unsigned)f2bf_bits(g1) << 16);
            }
        }
        // no barrier: g is read back by the same wave only (lgkmcnt ordering)

        // ---- res GEMM (Wr_h*g + Wr_l*g + I*x1_hi + I*x1_lo); stash g for deferred Gt ----
        const __hip_bfloat16* wr_hi = wr_hi_all + (size_t)lg * 1024;
        const __hip_bfloat16* wr_lo = wr_lo_all + (size_t)lg * 1024;
        bf16x8 arh[2], arl[2];
#pragma unroll
        for (int i = 0; i < 2; ++i) {
            int off = (16 * i + r) * 32 + q * 8;
            arh[i] = *(const bf16x8*)(wr_hi + off);
            arl[i] = *(const bf16x8*)(wr_lo + off);
        }
        f32x4 racc[2][2] = {};
#pragma unroll
        for (int jj = 0; jj < 2; ++jj) {
            int cn = c0 + 16 * jj + r;
            bf16x8 ghi = *(const bf16x8*)(yh + cn * 80 + q * 16);
            gstash[l][jj] = ghi;
            int r1 = cn + d; if (r1 > 127) r1 = 127;
            bf16x8 x1h = *(const bf16x8*)(xh + r1 * 80 + q * 16);
            bf16x8 x1l = *(const bf16x8*)(xl + r1 * 80 + q * 16);
#pragma unroll
            for (int i = 0; i < 2; ++i) {
                racc[i][jj] = __builtin_amdgcn_mfma_f32_16x16x32_bf16(arh[i], ghi, racc[i][jj], 0, 0, 0);
                racc[i][jj] = __builtin_amdgcn_mfma_f32_16x16x32_bf16(arl[i], ghi, racc[i][jj], 0, 0, 0);
                racc[i][jj] = __builtin_amdgcn_mfma_f32_16x16x32_bf16(aI[i], x1h, racc[i][jj], 0, 0, 0);
                racc[i][jj] = __builtin_amdgcn_mfma_f32_16x16x32_bf16(aI[i], x1l, racc[i][jj], 0, 0, 0);
            }
        }
        // no barrier: rows about to be overwritten belong to this wave only

        // ---- h_out (racc includes residual), RNE hi/lo ----
#pragma unroll
        for (int jj = 0; jj < 2; ++jj) {
            int cn = c0 + 16 * jj + r;
            int t = (u0 + cn) * S + p;
            bool wr_global = (l == 4) && (cn < v_out) && (t < L_out);
#pragma unroll
            for (int i = 0; i < 2; ++i) {
                int ch = 16 * i + 4 * q;
                float4 bb = *(const float4*)(br_all + lg * 32 + ch);
                float o0 = racc[i][jj][0] + bb.x;
                float o1 = racc[i][jj][1] + bb.y;
                float o2 = racc[i][jj][2] + bb.z;
                float o3 = racc[i][jj][3] + bb.w;
                ushort4 oh, ol;
                oh.x = f2bf_bits(o0); ol.x = f2bf_bits(o0 - bfb2f(oh.x));
                oh.y = f2bf_bits(o1); ol.y = f2bf_bits(o1 - bfb2f(oh.y));
                oh.z = f2bf_bits(o2); ol.z = f2bf_bits(o2 - bfb2f(oh.z));
                oh.w = f2bf_bits(o3); ol.w = f2bf_bits(o3 - bfb2f(oh.w));
                if (l == 4) {
                    if (wr_global) {
                        size_t base = ((size_t)b * L_out + t) * 32 + ch;
                        *(ushort4*)(hi_out + base) = oh;
                        *(ushort4*)(lo_out + base) = ol;
                    }
                } else {
                    int off = cn * 80 + ch * 2;
                    *(ushort4*)(yh + off) = oh;
                    *(ushort4*)(yl + off) = ol;
                }
            }
        }
        if (l < 4) {
            // prefetch next layer's ks=0 gate weights BEFORE the barrier:
            // loads are in flight while waves wait at s_barrier.
#pragma unroll
            for (int i = 0; i < 4; ++i) {
                int off = (16 * i + r) * 64 + q * 8;
                pfh[i] = *(const bf16x8*)(wg_hi_all + (size_t)(lg + 1) * 4096 + off);
                pfl[i] = *(const bf16x8*)(wg_lo_all + (size_t)(lg + 1) * 4096 + off);
            }
            __syncthreads();   // h visible to other waves' taps (no vmem stores pending)
        }
        cur = 2 - cur;
    }

    // ---- deferred Gt flush (after all barriers; drains once at kernel end) ----
#pragma unroll
    for (int l = 0; l < 5; ++l) {
        const int lg = l0 + l;
        const int L_out_l = L_in - S * ((2 << l) - 1);
        const int v_out_l = 129 - (2 << l);
        const int ws_l = L_out_l - OUT_LEN;
#pragma unroll
        for (int jj = 0; jj < 2; ++jj) {
            int cn = c0 + 16 * jj + r;
            int t = (u0 + cn) * S + p;
            if (cn < v_out_l && t >= ws_l && t < L_out_l) {
                size_t n = (size_t)b * OUT_LEN + (t - ws_l);
                *(bf16x8*)(Gt + n * 1600 + (size_t)lg * 32 + q * 8) = gstash[l][jj];
            }
        }
    }
}

// ---------------- MFMA GEMM, 256m x 128n tile, 512 thr, register-staged pipeline ----------------
// Loads for k+1 are prefetched into VGPRs (plain global loads) BEFORE computing k,
// then committed to LDS between two light barriers — removes the per-iteration
// vmcnt(0) drain of the load->barrier->compute structure (R17: MfmaUtil 29%).
// MODE 0: skip  -> Sb bf16 [n][512] = bf16(elu(acc+bias))
// MODE 1: post1+post2 fused -> out[n] += sum_m w2[m]*elu(acc+bias[m])  (f32 atomics)
template <int MODE>
__global__ __launch_bounds__(512) void mfma_gemm_kernel(
    const __hip_bfloat16* __restrict__ A, int lda,
    const __hip_bfloat16* __restrict__ B, int ldb,
    const float* __restrict__ bias, void* __restrict__ Cout,
    const float* __restrict__ w2, float* __restrict__ outp, int K)
{
    int id = blockIdx.x;
    int j = id >> 3;
    int m0 = (j & 1) * 256;
    int nt = (id & 7) + 8 * (j >> 1);
    if (nt >= N_TILES) return;
    int n0 = nt * 128;

    __shared__ __align__(16) char As[256 * 128];   // 32 KB
    __shared__ __align__(16) char Bs[128 * 128];   // 16 KB
    int tid = threadIdx.x;
    int lane = tid & 63, wave = tid >> 6;
    int wm = (wave & 3) * 64, wn = (wave >> 2) * 64;
    int q = lane >> 4, r = lane & 15;

    // per-thread staging slots (XOR-swizzled source chunks, lane-linear dests)
    int arow[4], acs[4], brow[2], bcs[2];
#pragma unroll
    for (int i = 0; i < 4; ++i) {
        int li = i * 512 + tid;
        arow[i] = li >> 3; acs[i] = ((li & 7) ^ (arow[i] & 7)) * 8;
    }
#pragma unroll
    for (int i = 0; i < 2; ++i) {
        int li = i * 512 + tid;
        int row = li >> 3;
        int gn = n0 + row; if (gn > NCOL - 1) gn = NCOL - 1;
        brow[i] = gn; bcs[i] = ((li & 7) ^ (row & 7)) * 8;
    }

    f32x4 acc[4][4] = {};
    uint4 pa[4], pb[2];

    // preload k=0 and commit to LDS
#pragma unroll
    for (int i = 0; i < 4; ++i)
        pa[i] = *(const uint4*)(A + (size_t)(m0 + arow[i]) * lda + acs[i]);
#pragma unroll
    for (int i = 0; i < 2; ++i)
        pb[i] = *(const uint4*)(B + (size_t)brow[i] * ldb + bcs[i]);
#pragma unroll
    for (int i = 0; i < 4; ++i) *(uint4*)(As + (i * 512 + tid) * 16) = pa[i];
#pragma unroll
    for (int i = 0; i < 2; ++i) *(uint4*)(Bs + (i * 512 + tid) * 16) = pb[i];
    __syncthreads();

    for (int k0 = 0; k0 < K; k0 += 64) {
        bool more = (k0 + 64 < K);
        if (more) {
#pragma unroll
            for (int i = 0; i < 4; ++i)
                pa[i] = *(const uint4*)(A + (size_t)(m0 + arow[i]) * lda + k0 + 64 + acs[i]);
#pragma unroll
            for (int i = 0; i < 2; ++i)
                pb[i] = *(const uint4*)(B + (size_t)brow[i] * ldb + k0 + 64 + bcs[i]);
        }
#pragma unroll
        for (int ks = 0; ks < 2; ++ks) {
            bf16x8 af[4], bfr[4];
#pragma unroll
            for (int s = 0; s < 4; ++s) {
                int m = wm + s * 16 + r;
                int cg = ks * 4 + q;
                af[s]  = *(const bf16x8*)(As + m * 128 + ((cg ^ (m & 7)) * 16));
                int n = wn + s * 16 + r;
                bfr[s] = *(const bf16x8*)(Bs + n * 128 + ((cg ^ (n & 7)) * 16));
            }
#pragma unroll
            for (int i = 0; i < 4; ++i)
#pragma unroll
                for (int jx = 0; jx < 4; ++jx)
                    acc[i][jx] = __builtin_amdgcn_mfma_f32_16x16x32_bf16(
                        af[i], bfr[jx], acc[i][jx], 0, 0, 0);
        }
        if (more) {
            __syncthreads();   // all waves done reading As/Bs for k0
#pragma unroll
            for (int i = 0; i < 4; ++i) *(uint4*)(As + (i * 512 + tid) * 16) = pa[i];
#pragma unroll
            for (int i = 0; i < 2; ++i) *(uint4*)(Bs + (i * 512 + tid) * 16) = pb[i];
            __syncthreads();   // new tiles visible
        }
    }

    if (MODE == 0) {
        __hip_bfloat16* Sb = (__hip_bfloat16*)Cout;
#pragma unroll
        for (int jx = 0; jx < 4; ++jx) {
            int n = n0 + wn + jx * 16 + r;
            if (n >= NCOL) continue;
#pragma unroll
            for (int i = 0; i < 4; ++i) {
                int mb = m0 + wm + i * 16 + q * 4;
                float4 bs = *(const float4*)(bias + mb);
                ushort4 u;
                u.x = f2bf_bits(eluf(acc[i][jx][0] + bs.x));
                u.y = f2bf_bits(eluf(acc[i][jx][1] + bs.y));
                u.z = f2bf_bits(eluf(acc[i][jx][2] + bs.z));
                u.w = f2bf_bits(eluf(acc[i][jx][3] + bs.w));
                *(ushort4*)(Sb + (size_t)n * 512 + mb) = u;
            }
        }
    } else {
        // fused post1+post2: out[n] += sum_m w2[m]*elu(y1[m][n])
        float part[4] = {0.0f, 0.0f, 0.0f, 0.0f};
#pragma unroll
        for (int i = 0; i < 4; ++i) {
            int mb = m0 + wm + i * 16 + q * 4;
            float4 bs = *(const float4*)(bias + mb);
            float4 wv = *(const float4*)(w2 + mb);
#pragma unroll
            for (int jx = 0; jx < 4; ++jx) {
                part[jx] += wv.x * eluf(acc[i][jx][0] + bs.x);
                part[jx] += wv.y * eluf(acc[i][jx][1] + bs.y);
                part[jx] += wv.z * eluf(acc[i][jx][2] + bs.z);
                part[jx] += wv.w * eluf(acc[i][jx][3] + bs.w);
            }
        }
#pragma unroll
        for (int jx = 0; jx < 4; ++jx) {
            float v = part[jx];
            v += __shfl_xor(v, 16, 64);
            v += __shfl_xor(v, 32, 64);
            int n = n0 + wn + jx * 16 + r;
            if (q == 0 && n < NCOL) atomicAdd(outp + n, v);
        }
    }
}

// ---------------- out init: out[n] = b_post2 (d_out is re-poisoned each replay) ----------------
__global__ __launch_bounds__(256) void init_out_kernel(
    const float* __restrict__ b2, float* __restrict__ out, int N)
{
    int n = blockIdx.x * 256 + threadIdx.x;
    if (n < N) out[n] = b2[0];
}

extern "C" void kernel_launch(void* const* d_in, const int* in_sizes, int n_in,
                              void* d_out, int out_size, void* d_ws, size_t ws_size,
                              hipStream_t stream)
{
    const float* x      = (const float*)d_in[0];
    const float* w_in   = (const float*)d_in[1];
    const float* b_in   = (const float*)d_in[2];
    const float* w_sig  = (const float*)d_in[3];
    const float* b_sig  = (const float*)d_in[4];
    const float* w_tanh = (const float*)d_in[5];
    const float* b_tanh = (const float*)d_in[6];
    const float* w_skip = (const float*)d_in[7];
    const float* b_skip = (const float*)d_in[8];
    const float* w_res  = (const float*)d_in[9];
    const float* b_res  = (const float*)d_in[10];
    const float* w_post1 = (const float*)d_in[11];
    const float* b_post1 = (const float*)d_in[12];
    const float* w_post2 = (const float*)d_in[13];
    const float* b_post2 = (const float*)d_in[14];
    float* out = (float*)d_out;

    char* ws = (char*)d_ws;
    __hip_bfloat16* hAh = (__hip_bfloat16*)(ws + OFF_HAH);
    __hip_bfloat16* hAl = (__hip_bfloat16*)(ws + OFF_HAL);
    __hip_bfloat16* hBh = (__hip_bfloat16*)(ws + OFF_HBH);
    __hip_bfloat16* hBl = (__hip_bfloat16*)(ws + OFF_HBL);
    __hip_bfloat16* wgh = (__hip_bfloat16*)(ws + OFF_WGH);
    __hip_bfloat16* wgl = (__hip_bfloat16*)(ws + OFF_WGL);
    __hip_bfloat16* wrh = (__hip_bfloat16*)(ws + OFF_WRH);
    __hip_bfloat16* wrl = (__hip_bfloat16*)(ws + OFF_WRL);
    float* bgate = (float*)(ws + OFF_BG);
    __hip_bfloat16* Apack  = (__hip_bfloat16*)(ws + OFF_AP);
    __hip_bfloat16* w1pack = (__hip_bfloat16*)(ws + OFF_W1P);
    float* bsum = (float*)(ws + OFF_BS);
    __hip_bfloat16* Sb = (__hip_bfloat16*)(ws + OFF_SB);
    __hip_bfloat16* Gt = (__hip_bfloat16*)(ws + OFF_GT);

    in_conv_kernel<<<dim3(T_IN / 32, BATCH), 256, 0, stream>>>(x, w_in, b_in, hAh, hAl);
    pack_kernel<<<dim3(512 * 1600 / 256), 256, 0, stream>>>(
        w_skip, b_skip, w_post1, w_sig, w_tanh, w_res, b_sig, b_tanh,
        Apack, w1pack, wgh, wgl, wrh, wrl, bgate, bsum);

    int L = T_IN;
    __hip_bfloat16 *cih = hAh, *cil = hAl, *coh = hBh, *col_ = hBl;
    for (int rep = 0; rep < 5; ++rep) {
        {   // group A: layers rep*10 .. +4, d=1..16 (S=1)
            int out_len = L - 31;
            int n_ut = (out_len + 95) / 96;
            group_kernel<1><<<dim3(BATCH * n_ut), 256, 0, stream>>>(
                cih, cil, coh, col_, Gt, wgh, wgl, wrh, wrl, bgate, b_res,
                rep * 10, L, n_ut);
            L = out_len;
            __hip_bfloat16* t1 = cih; cih = coh; coh = t1;
            __hip_bfloat16* t2 = cil; cil = col_; col_ = t2;
        }
        {   // group B: layers rep*10+5 .. +9, d=32..512 (S=32 polyphase)
            int U = (L + 31) / 32;
            int out_u = U - 31; if (out_u < 1) out_u = 1;
            int n_ut = (out_u + 95) / 96;
            group_kernel<32><<<dim3(BATCH * 32 * n_ut), 256, 0, stream>>>(
                cih, cil, coh, col_, Gt, wgh, wgl, wrh, wrl, bgate, b_res,
                rep * 10 + 5, L, n_ut);
            L = L - 992;
            __hip_bfloat16* t1 = cih; cih = coh; coh = t1;
            __hip_bfloat16* t2 = cil; cil = col_; col_ = t2;
        }
    }

    // skip GEMM: Sb[n][512] = bf16(elu(Apack(512x1600) * Gt^T + bsum))
    mfma_gemm_kernel<0><<<dim3(400), 512, 0, stream>>>(
        Apack, 1600, Gt, 1600, bsum, (void*)Sb, nullptr, nullptr, 1600);
    // out[n] = b_post2
    init_out_kernel<<<dim3((NCOL + 255) / 256), 256, 0, stream>>>(b_post2, out, NCOL);
    // fused post1+post2: out[n] += sum_m w2[m]*elu(W1*Sb^T + b_post1)
    mfma_gemm_kernel<1><<<dim3(400), 512, 0, stream>>>(
        w1pack, 512, Sb, 512, b_post1, nullptr, w_post2, out, 512);
}

// Round 19
// 530.311 us; speedup vs baseline: 1.3116x; 1.3116x over previous
//
#include <hip/hip_runtime.h>
#include <hip/hip_bf16.h>

#define N_LAYERS 50
#define N_RES 32
#define N_SKIP 512
#define N_FEAT 8
#define BATCH 8
#define T_IN 8192
#define OUT_LEN 3077
#define NCOL (BATCH * OUT_LEN)   // 24616
#define N_TILES ((NCOL + 127) / 128)   // 193

typedef __bf16 bf16x8 __attribute__((ext_vector_type(8)));
typedef float  f32x4  __attribute__((ext_vector_type(4)));

// ---------------- workspace layout (bytes) ----------------
#define SZ_HP    ((size_t)BATCH * T_IN * 32 * 2)            // 4 MB per plane
#define OFF_HAH  ((size_t)0)
#define OFF_HAL  (OFF_HAH + SZ_HP)
#define OFF_HBH  (OFF_HAL + SZ_HP)
#define OFF_HBL  (OFF_HBH + SZ_HP)
#define OFF_WGH  (OFF_HBL + SZ_HP)                          // wg hi bf16 [50][64][64]
#define SZ_WG    ((size_t)50 * 64 * 64 * 2)
#define OFF_WGL  (OFF_WGH + SZ_WG)
#define OFF_WRH  (OFF_WGL + SZ_WG)                          // wr hi bf16 [50][32][32]
#define SZ_WR    ((size_t)50 * 32 * 32 * 2)
#define OFF_WRL  (OFF_WRH + SZ_WR)
#define OFF_BG   (OFF_WRL + SZ_WR)                          // bgate f32 [50][64]
#define SZ_BG    ((size_t)50 * 64 * 4)
#define OFF_AP   (OFF_BG + SZ_BG)                           // Apack bf16 [512][1600]
#define SZ_AP    ((size_t)512 * 1600 * 2)
#define OFF_W1P  (OFF_AP + SZ_AP)                           // w1pack bf16 [512][512]
#define SZ_W1P   ((size_t)512 * 512 * 2)
#define OFF_BS   (OFF_W1P + SZ_W1P)                         // bsum f32 [512]
#define SZ_BS    ((size_t)2048)
#define OFF_SB   (OFF_BS + SZ_BS)                           // Sb bf16 [NCOL][512] (elu applied)
#define SZ_SB    ((size_t)NCOL * 512 * 2)
#define OFF_GT   (OFF_SB + SZ_SB)                           // Gt bf16 [NCOL][1600]
#define SZ_GT    ((size_t)NCOL * 1600 * 2)

__device__ __forceinline__ float eluf(float v) {
    return v > 0.0f ? v : (__expf(v) - 1.0f);
}
__device__ __forceinline__ unsigned short f2bf_bits(float f) {
    __hip_bfloat16 h = __float2bfloat16(f);
    return *(unsigned short*)&h;
}
__device__ __forceinline__ float bfb2f(unsigned short u) {
    return __uint_as_float((unsigned)u << 16);
}
__device__ __forceinline__ void gl_lds16(const void* g, void* l) {
    __builtin_amdgcn_global_load_lds(
        (const __attribute__((address_space(1))) void*)g,
        (__attribute__((address_space(3))) void*)l, 16, 0, 0);
}

// ---------------- input 1x1 conv -> h0 hi/lo planes [b][t][32] ----------------
__global__ __launch_bounds__(256) void in_conv_kernel(
    const float* __restrict__ x, const float* __restrict__ w_in,
    const float* __restrict__ b_in,
    __hip_bfloat16* __restrict__ h_hi, __hip_bfloat16* __restrict__ h_lo)
{
    int tid = threadIdx.x;
    int t = blockIdx.x * 32 + (tid >> 3);
    int grp = tid & 7;
    int b = blockIdx.y;
    const float* xp = x + ((size_t)b * T_IN + t) * 8;
    float4 v0 = *(const float4*)xp;
    float4 v1 = *(const float4*)(xp + 4);
    float xv[8] = {v0.x, v0.y, v0.z, v0.w, v1.x, v1.y, v1.z, v1.w};
    ushort4 oh, ol;
    unsigned short hb[4], lb[4];
#pragma unroll
    for (int e = 0; e < 4; ++e) {
        int oc = grp * 4 + e;
        float acc = b_in[oc];
#pragma unroll
        for (int f = 0; f < 8; ++f) acc += w_in[oc * 8 + f] * xv[f];
        hb[e] = f2bf_bits(acc);
        lb[e] = f2bf_bits(acc - bfb2f(hb[e]));
    }
    oh.x = hb[0]; oh.y = hb[1]; oh.z = hb[2]; oh.w = hb[3];
    ol.x = lb[0]; ol.y = lb[1]; ol.z = lb[2]; ol.w = lb[3];
    size_t base = ((size_t)b * T_IN + t) * 32 + grp * 4;
    *(ushort4*)(h_hi + base) = oh;
    *(ushort4*)(h_lo + base) = ol;
}

// ---------------- pack weights (hi/lo where needed) ----------------
__global__ __launch_bounds__(256) void pack_kernel(
    const float* __restrict__ w_skip, const float* __restrict__ b_skip,
    const float* __restrict__ w_post1,
    const float* __restrict__ w_sig, const float* __restrict__ w_tanh,
    const float* __restrict__ w_res,
    const float* __restrict__ b_sig, const float* __restrict__ b_tanh,
    __hip_bfloat16* __restrict__ Apack, __hip_bfloat16* __restrict__ w1pack,
    __hip_bfloat16* __restrict__ wg_hi, __hip_bfloat16* __restrict__ wg_lo,
    __hip_bfloat16* __restrict__ wr_hi, __hip_bfloat16* __restrict__ wr_lo,
    float* __restrict__ bgate, float* __restrict__ bsum)
{
    int tid = blockIdx.x * 256 + threadIdx.x;    // 0 .. 819199
    {   // Apack[m][i*32+c] = bf16(w_skip[i][m][c])
        int m = tid / 1600;
        int r = tid - m * 1600;
        int i = r >> 5, c = r & 31;
        Apack[tid] = __float2bfloat16(w_skip[((size_t)i * 512 + m) * 32 + c]);
    }
    if (tid < 512 * 512) w1pack[tid] = __float2bfloat16(w_post1[tid]);
    if (tid < 50 * 64 * 64) {     // wg[l][row=2c+f][k=tap*32+ci]
        int l = tid >> 12;
        int rem = tid & 4095;
        int row = rem >> 6, k = rem & 63;
        int c = row >> 1, f = row & 1;
        int tap = k >> 5, ci = k & 31;
        const float* src = f ? w_tanh : w_sig;
        float v = src[(((size_t)l * 32 + c) * 32 + ci) * 2 + tap];
        unsigned short h = f2bf_bits(v);
        wg_hi[tid] = __float2bfloat16(v);
        wg_lo[tid] = __float2bfloat16(v - bfb2f(h));
    }
    if (tid < 50 * 1024) {
        float v = w_res[tid];
        unsigned short h = f2bf_bits(v);
        wr_hi[tid] = __float2bfloat16(v);
        wr_lo[tid] = __float2bfloat16(v - bfb2f(h));
    }
    if (tid < 50 * 64) {
        int l = tid >> 6, row = tid & 63;
        bgate[tid] = (row & 1) ? b_tanh[l * 32 + (row >> 1)] : b_sig[l * 32 + (row >> 1)];
    }
    if (tid < 512) {
        float s = 0.0f;
        for (int l = 0; l < N_LAYERS; ++l) s += b_skip[l * 512 + tid];
        bsum[tid] = s;
    }
}

// ---------------- 5 fused dilated layers, LDS-resident (R17 base + lane remap) ----------------
template <int S>
__global__ __launch_bounds__(256, 4) void group_kernel(
    const __hip_bfloat16* __restrict__ hi_in, const __hip_bfloat16* __restrict__ lo_in,
    __hip_bfloat16* __restrict__ hi_out, __hip_bfloat16* __restrict__ lo_out,
    __hip_bfloat16* __restrict__ Gt,
    const __hip_bfloat16* __restrict__ wg_hi_all, const __hip_bfloat16* __restrict__ wg_lo_all,
    const __hip_bfloat16* __restrict__ wr_hi_all, const __hip_bfloat16* __restrict__ wr_lo_all,
    const float* __restrict__ bg_all, const float* __restrict__ br_all,
    int l0, int L_in, int n_ut)
{
    __shared__ __align__(16) char lds[4][128 * 80];   // {hiA, loA, hiB, loB}
    const int tid = threadIdx.x;
    const int lane = tid & 63;
    const int wave = tid >> 6;
    const int q = lane >> 4, r = lane & 15;
    const int c0 = wave * 32;

    int bid = blockIdx.x;
    int u_t = bid % n_ut;
    int rest = bid / n_ut;
    int p = rest % S;
    int b = rest / S;
    int u0 = u_t * 96;
    int u_last = (L_in - 1 - p) / S;

    // identity A-frags for residual injection: aI[i][m=r][k=8q+j] = (k == r+16i)
    bf16x8 aI[2];
    {
        union { bf16x8 v; unsigned short u[8]; } t0, t1;
#pragma unroll
        for (int e = 0; e < 8; ++e) { t0.u[e] = 0; t1.u[e] = 0; }
        int j0 = r - 8 * q;
        int j1 = r + 16 - 8 * q;
        if (j0 >= 0 && j0 < 8) t0.u[j0] = 0x3F80;
        if (j1 >= 0 && j1 < 8) t1.u[j1] = 0x3F80;
        aI[0] = t0.v; aI[1] = t1.v;
    }

    // ---- prefetch layer-0 ks=0 gate weights (in flight during staging) ----
    bf16x8 pfh[4], pfl[4];
#pragma unroll
    for (int i = 0; i < 4; ++i) {
        int off = (16 * i + r) * 64 + q * 8;
        pfh[i] = *(const bf16x8*)(wg_hi_all + (size_t)l0 * 4096 + off);
        pfl[i] = *(const bf16x8*)(wg_lo_all + (size_t)l0 * 4096 + off);
    }

    // ---- stage input tile: rows u0..u0+127 (clamped); lane-linear rows ----
    {
        int row = tid & 127, seg = tid >> 7;
        int u = u0 + row; if (u > u_last) u = u_last;
        size_t gb = ((size_t)b * L_in + (size_t)u * S + p) * 32 + seg * 16;
        int lb = row * 80 + seg * 32;
        uint4 a0 = *(const uint4*)(hi_in + gb);
        uint4 a1 = *(const uint4*)(hi_in + gb + 8);
        uint4 c0v = *(const uint4*)(lo_in + gb);
        uint4 c1v = *(const uint4*)(lo_in + gb + 8);
        *(uint4*)(lds[0] + lb) = a0; *(uint4*)(lds[0] + lb + 16) = a1;
        *(uint4*)(lds[1] + lb) = c0v; *(uint4*)(lds[1] + lb + 16) = c1v;
    }
    __syncthreads();

    bf16x8 gstash[5][2];   // deferred Gt payloads (registers; loop unrolled)

    int cur = 0;
#pragma unroll
    for (int l = 0; l < 5; ++l) {
        const int d = 1 << l;
        const int lg = l0 + l;
        const int L_out = L_in - S * ((2 << l) - 1);
        const int v_out = 129 - (2 << l);
        const char* xh = lds[cur];
        const char* xl = lds[cur + 1];
        char* yh = lds[2 - cur];
        char* yl = lds[3 - cur];

        const __hip_bfloat16* wg_hi = wg_hi_all + (size_t)lg * 4096;
        const __hip_bfloat16* wg_lo = wg_lo_all + (size_t)lg * 4096;
        float4 bgv[4];
#pragma unroll
        for (int i = 0; i < 4; ++i) bgv[i] = *(const float4*)(bg_all + lg * 64 + 16 * i + 4 * q);

        // ---- gate GEMM: ks=0 uses prefetched frags; ks=1 loads inline ----
        f32x4 acc[4][2] = {};
#pragma unroll
        for (int ks = 0; ks < 2; ++ks) {
            bf16x8 afh[4], afl[4];
            if (ks == 0) {
#pragma unroll
                for (int i = 0; i < 4; ++i) { afh[i] = pfh[i]; afl[i] = pfl[i]; }
            } else {
#pragma unroll
                for (int i = 0; i < 4; ++i) {
                    int off = (16 * i + r) * 64 + 32 + q * 8;
                    afh[i] = *(const bf16x8*)(wg_hi + off);
                    afl[i] = *(const bf16x8*)(wg_lo + off);
                }
            }
#pragma unroll
            for (int jj = 0; jj < 2; ++jj) {
                int cn = c0 + 16 * jj + r;
                int rowk = cn;
                if (ks) { rowk = cn + d; if (rowk > 127) rowk = 127; }
                bf16x8 bhi = *(const bf16x8*)(xh + rowk * 80 + q * 16);
                bf16x8 blo = *(const bf16x8*)(xl + rowk * 80 + q * 16);
#pragma unroll
                for (int i = 0; i < 4; ++i) {
                    acc[i][jj] = __builtin_amdgcn_mfma_f32_16x16x32_bf16(afh[i], bhi, acc[i][jj], 0, 0, 0);
                    acc[i][jj] = __builtin_amdgcn_mfma_f32_16x16x32_bf16(afh[i], blo, acc[i][jj], 0, 0, 0);
                    acc[i][jj] = __builtin_amdgcn_mfma_f32_16x16x32_bf16(afl[i], bhi, acc[i][jj], 0, 0, 0);
                }
            }
        }

        // ---- gates -> yh (hi only; own cols; within-wave, no barrier) ----
#pragma unroll
        for (int i = 0; i < 4; ++i) {
#pragma unroll
            for (int jj = 0; jj < 2; ++jj) {
                int cn = c0 + 16 * jj + r;
                float ps0 = acc[i][jj][0] + bgv[i].x;
                float pt0 = acc[i][jj][1] + bgv[i].y;
                float ps1 = acc[i][jj][2] + bgv[i].z;
                float pt1 = acc[i][jj][3] + bgv[i].w;
                float g0 = __builtin_amdgcn_rcpf(1.0f + __expf(-ps0)) *
                           (1.0f - 2.0f * __builtin_amdgcn_rcpf(__expf(2.0f * pt0) + 1.0f));
                float g1 = __builtin_amdgcn_rcpf(1.0f + __expf(-ps1)) *
                           (1.0f - 2.0f * __builtin_amdgcn_rcpf(__expf(2.0f * pt1) + 1.0f));
                *(unsigned int*)(yh + cn * 80 + 16 * i + 4 * q) =
                    (unsigned)f2bf_bits(g0) | ((unsigned)f2bf_bits(g1) << 16);
            }
        }
        // no barrier: g is read back by the same wave only (lgkmcnt ordering)

        // ---- res GEMM (Wr_h*g + Wr_l*g + I*x1_hi + I*x1_lo); stash g for deferred Gt ----
        const __hip_bfloat16* wr_hi = wr_hi_all + (size_t)lg * 1024;
        const __hip_bfloat16* wr_lo = wr_lo_all + (size_t)lg * 1024;
        bf16x8 arh[2], arl[2];
#pragma unroll
        for (int i = 0; i < 2; ++i) {
            int off = (16 * i + r) * 32 + q * 8;
            arh[i] = *(const bf16x8*)(wr_hi + off);
            arl[i] = *(const bf16x8*)(wr_lo + off);
        }
        f32x4 racc[2][2] = {};
#pragma unroll
        for (int jj = 0; jj < 2; ++jj) {
            int cn = c0 + 16 * jj + r;
            bf16x8 ghi = *(const bf16x8*)(yh + cn * 80 + q * 16);
            gstash[l][jj] = ghi;
            int r1 = cn + d; if (r1 > 127) r1 = 127;
            bf16x8 x1h = *(const bf16x8*)(xh + r1 * 80 + q * 16);
            bf16x8 x1l = *(const bf16x8*)(xl + r1 * 80 + q * 16);
#pragma unroll
            for (int i = 0; i < 2; ++i) {
                racc[i][jj] = __builtin_amdgcn_mfma_f32_16x16x32_bf16(arh[i], ghi, racc[i][jj], 0, 0, 0);
                racc[i][jj] = __builtin_amdgcn_mfma_f32_16x16x32_bf16(arl[i], ghi, racc[i][jj], 0, 0, 0);
                racc[i][jj] = __builtin_amdgcn_mfma_f32_16x16x32_bf16(aI[i], x1h, racc[i][jj], 0, 0, 0);
                racc[i][jj] = __builtin_amdgcn_mfma_f32_16x16x32_bf16(aI[i], x1l, racc[i][jj], 0, 0, 0);
            }
        }
        // no barrier: rows about to be overwritten belong to this wave only

        // ---- h_out (racc includes residual), RNE hi/lo ----
#pragma unroll
        for (int jj = 0; jj < 2; ++jj) {
            int cn = c0 + 16 * jj + r;
            int t = (u0 + cn) * S + p;
            bool wr_global = (l == 4) && (cn < v_out) && (t < L_out);
#pragma unroll
            for (int i = 0; i < 2; ++i) {
                int ch = 16 * i + 4 * q;
                float4 bb = *(const float4*)(br_all + lg * 32 + ch);
                float o0 = racc[i][jj][0] + bb.x;
                float o1 = racc[i][jj][1] + bb.y;
                float o2 = racc[i][jj][2] + bb.z;
                float o3 = racc[i][jj][3] + bb.w;
                ushort4 oh, ol;
                oh.x = f2bf_bits(o0); ol.x = f2bf_bits(o0 - bfb2f(oh.x));
                oh.y = f2bf_bits(o1); ol.y = f2bf_bits(o1 - bfb2f(oh.y));
                oh.z = f2bf_bits(o2); ol.z = f2bf_bits(o2 - bfb2f(oh.z));
                oh.w = f2bf_bits(o3); ol.w = f2bf_bits(o3 - bfb2f(oh.w));
                if (l == 4) {
                    if (wr_global) {
                        size_t base = ((size_t)b * L_out + t) * 32 + ch;
                        *(ushort4*)(hi_out + base) = oh;
                        *(ushort4*)(lo_out + base) = ol;
                    }
                } else {
                    int off = cn * 80 + ch * 2;
                    *(ushort4*)(yh + off) = oh;
                    *(ushort4*)(yl + off) = ol;
                }
            }
        }
        if (l < 4) {
            // prefetch next layer's ks=0 gate weights BEFORE the barrier
#pragma unroll
            for (int i = 0; i < 4; ++i) {
                int off = (16 * i + r) * 64 + q * 8;
                pfh[i] = *(const bf16x8*)(wg_hi_all + (size_t)(lg + 1) * 4096 + off);
                pfl[i] = *(const bf16x8*)(wg_lo_all + (size_t)(lg + 1) * 4096 + off);
            }
            __syncthreads();   // h visible to other waves' taps (no vmem stores pending)
        }
        cur = 2 - cur;
    }

    // ---- deferred Gt flush (after all barriers; drains once at kernel end) ----
#pragma unroll
    for (int l = 0; l < 5; ++l) {
        const int lg = l0 + l;
        const int L_out_l = L_in - S * ((2 << l) - 1);
        const int v_out_l = 129 - (2 << l);
        const int ws_l = L_out_l - OUT_LEN;
#pragma unroll
        for (int jj = 0; jj < 2; ++jj) {
            int cn = c0 + 16 * jj + r;
            int t = (u0 + cn) * S + p;
            if (cn < v_out_l && t >= ws_l && t < L_out_l) {
                size_t n = (size_t)b * OUT_LEN + (t - ws_l);
                *(bf16x8*)(Gt + n * 1600 + (size_t)lg * 32 + q * 8) = gstash[l][jj];
            }
        }
    }
}

// ---------------- MFMA GEMM, 256m x 128n tile, 512 thr (R17 proven form) ----------------
// MODE 0: skip  -> Sb bf16 [n][512] = bf16(elu(acc+bias))
// MODE 1: post1+post2 fused -> out[n] += sum_m w2[m]*elu(acc+bias[m])  (f32 atomics)
template <int MODE>
__global__ __launch_bounds__(512) void mfma_gemm_kernel(
    const __hip_bfloat16* __restrict__ A, int lda,
    const __hip_bfloat16* __restrict__ B, int ldb,
    const float* __restrict__ bias, void* __restrict__ Cout,
    const float* __restrict__ w2, float* __restrict__ outp, int K)
{
    int id = blockIdx.x;
    int j = id >> 3;
    int m0 = (j & 1) * 256;
    int nt = (id & 7) + 8 * (j >> 1);
    if (nt >= N_TILES) return;
    int n0 = nt * 128;

    __shared__ __align__(16) char As[256 * 128];   // 32 KB
    __shared__ __align__(16) char Bs[128 * 128];   // 16 KB
    int tid = threadIdx.x;
    int lane = tid & 63, wave = tid >> 6;
    int wm = (wave & 3) * 64, wn = (wave >> 2) * 64;
    int q = lane >> 4, r = lane & 15;

    f32x4 acc[4][4] = {};

    for (int k0 = 0; k0 < K; k0 += 64) {
        __syncthreads();
#pragma unroll
        for (int i = 0; i < 4; ++i) {          // A: 2048 16B-slots
            int li = i * 512 + tid;
            int row = li >> 3, ch = li & 7;
            int cs = (ch ^ (row & 7)) * 8;
            gl_lds16(A + (size_t)(m0 + row) * lda + k0 + cs, As + li * 16);
        }
#pragma unroll
        for (int i = 0; i < 2; ++i) {          // B: 1024 16B-slots
            int li = i * 512 + tid;
            int row = li >> 3, ch = li & 7;
            int cs = (ch ^ (row & 7)) * 8;
            int gn = n0 + row; if (gn > NCOL - 1) gn = NCOL - 1;
            gl_lds16(B + (size_t)gn * ldb + k0 + cs, Bs + li * 16);
        }
        __syncthreads();
#pragma unroll
        for (int ks = 0; ks < 2; ++ks) {
            bf16x8 af[4], bfr[4];
#pragma unroll
            for (int s = 0; s < 4; ++s) {
                int m = wm + s * 16 + r;
                int cg = ks * 4 + q;
                af[s]  = *(const bf16x8*)(As + m * 128 + ((cg ^ (m & 7)) * 16));
                int n = wn + s * 16 + r;
                bfr[s] = *(const bf16x8*)(Bs + n * 128 + ((cg ^ (n & 7)) * 16));
            }
#pragma unroll
            for (int i = 0; i < 4; ++i)
#pragma unroll
                for (int jx = 0; jx < 4; ++jx)
                    acc[i][jx] = __builtin_amdgcn_mfma_f32_16x16x32_bf16(
                        af[i], bfr[jx], acc[i][jx], 0, 0, 0);
        }
    }

    if (MODE == 0) {
        __hip_bfloat16* Sb = (__hip_bfloat16*)Cout;
#pragma unroll
        for (int jx = 0; jx < 4; ++jx) {
            int n = n0 + wn + jx * 16 + r;
            if (n >= NCOL) continue;
#pragma unroll
            for (int i = 0; i < 4; ++i) {
                int mb = m0 + wm + i * 16 + q * 4;
                float4 bs = *(const float4*)(bias + mb);
                ushort4 u;
                u.x = f2bf_bits(eluf(acc[i][jx][0] + bs.x));
                u.y = f2bf_bits(eluf(acc[i][jx][1] + bs.y));
                u.z = f2bf_bits(eluf(acc[i][jx][2] + bs.z));
                u.w = f2bf_bits(eluf(acc[i][jx][3] + bs.w));
                *(ushort4*)(Sb + (size_t)n * 512 + mb) = u;
            }
        }
    } else {
        // fused post1+post2: out[n] += sum_m w2[m]*elu(y1[m][n])
        float part[4] = {0.0f, 0.0f, 0.0f, 0.0f};
#pragma unroll
        for (int i = 0; i < 4; ++i) {
            int mb = m0 + wm + i * 16 + q * 4;
            float4 bs = *(const float4*)(bias + mb);
            float4 wv = *(const float4*)(w2 + mb);
#pragma unroll
            for (int jx = 0; jx < 4; ++jx) {
                part[jx] += wv.x * eluf(acc[i][jx][0] + bs.x);
                part[jx] += wv.y * eluf(acc[i][jx][1] + bs.y);
                part[jx] += wv.z * eluf(acc[i][jx][2] + bs.z);
                part[jx] += wv.w * eluf(acc[i][jx][3] + bs.w);
            }
        }
#pragma unroll
        for (int jx = 0; jx < 4; ++jx) {
            float v = part[jx];
            v += __shfl_xor(v, 16, 64);
            v += __shfl_xor(v, 32, 64);
            int n = n0 + wn + jx * 16 + r;
            if (q == 0 && n < NCOL) atomicAdd(outp + n, v);
        }
    }
}

// ---------------- out init: out[n] = b_post2 (d_out is re-poisoned each replay) ----------------
__global__ __launch_bounds__(256) void init_out_kernel(
    const float* __restrict__ b2, float* __restrict__ out, int N)
{
    int n = blockIdx.x * 256 + threadIdx.x;
    if (n < N) out[n] = b2[0];
}

extern "C" void kernel_launch(void* const* d_in, const int* in_sizes, int n_in,
                              void* d_out, int out_size, void* d_ws, size_t ws_size,
                              hipStream_t stream)
{
    const float* x      = (const float*)d_in[0];
    const float* w_in   = (const float*)d_in[1];
    const float* b_in   = (const float*)d_in[2];
    const float* w_sig  = (const float*)d_in[3];
    const float* b_sig  = (const float*)d_in[4];
    const float* w_tanh = (const float*)d_in[5];
    const float* b_tanh = (const float*)d_in[6];
    const float* w_skip = (const float*)d_in[7];
    const float* b_skip = (const float*)d_in[8];
    const float* w_res  = (const float*)d_in[9];
    const float* b_res  = (const float*)d_in[10];
    const float* w_post1 = (const float*)d_in[11];
    const float* b_post1 = (const float*)d_in[12];
    const float* w_post2 = (const float*)d_in[13];
    const float* b_post2 = (const float*)d_in[14];
    float* out = (float*)d_out;

    char* ws = (char*)d_ws;
    __hip_bfloat16* hAh = (__hip_bfloat16*)(ws + OFF_HAH);
    __hip_bfloat16* hAl = (__hip_bfloat16*)(ws + OFF_HAL);
    __hip_bfloat16* hBh = (__hip_bfloat16*)(ws + OFF_HBH);
    __hip_bfloat16* hBl = (__hip_bfloat16*)(ws + OFF_HBL);
    __hip_bfloat16* wgh = (__hip_bfloat16*)(ws + OFF_WGH);
    __hip_bfloat16* wgl = (__hip_bfloat16*)(ws + OFF_WGL);
    __hip_bfloat16* wrh = (__hip_bfloat16*)(ws + OFF_WRH);
    __hip_bfloat16* wrl = (__hip_bfloat16*)(ws + OFF_WRL);
    float* bgate = (float*)(ws + OFF_BG);
    __hip_bfloat16* Apack  = (__hip_bfloat16*)(ws + OFF_AP);
    __hip_bfloat16* w1pack = (__hip_bfloat16*)(ws + OFF_W1P);
    float* bsum = (float*)(ws + OFF_BS);
    __hip_bfloat16* Sb = (__hip_bfloat16*)(ws + OFF_SB);
    __hip_bfloat16* Gt = (__hip_bfloat16*)(ws + OFF_GT);

    in_conv_kernel<<<dim3(T_IN / 32, BATCH), 256, 0, stream>>>(x, w_in, b_in, hAh, hAl);
    pack_kernel<<<dim3(512 * 1600 / 256), 256, 0, stream>>>(
        w_skip, b_skip, w_post1, w_sig, w_tanh, w_res, b_sig, b_tanh,
        Apack, w1pack, wgh, wgl, wrh, wrl, bgate, bsum);

    int L = T_IN;
    __hip_bfloat16 *cih = hAh, *cil = hAl, *coh = hBh, *col_ = hBl;
    for (int rep = 0; rep < 5; ++rep) {
        {   // group A: layers rep*10 .. +4, d=1..16 (S=1)
            int out_len = L - 31;
            int n_ut = (out_len + 95) / 96;
            group_kernel<1><<<dim3(BATCH * n_ut), 256, 0, stream>>>(
                cih, cil, coh, col_, Gt, wgh, wgl, wrh, wrl, bgate, b_res,
                rep * 10, L, n_ut);
            L = out_len;
            __hip_bfloat16* t1 = cih; cih = coh; coh = t1;
            __hip_bfloat16* t2 = cil; cil = col_; col_ = t2;
        }
        {   // group B: layers rep*10+5 .. +9, d=32..512 (S=32 polyphase)
            int U = (L + 31) / 32;
            int out_u = U - 31; if (out_u < 1) out_u = 1;
            int n_ut = (out_u + 95) / 96;
            group_kernel<32><<<dim3(BATCH * 32 * n_ut), 256, 0, stream>>>(
                cih, cil, coh, col_, Gt, wgh, wgl, wrh, wrl, bgate, b_res,
                rep * 10 + 5, L, n_ut);
            L = L - 992;
            __hip_bfloat16* t1 = cih; cih = coh; coh = t1;
            __hip_bfloat16* t2 = cil; cil = col_; col_ = t2;
        }
    }

    // skip GEMM: Sb[n][512] = bf16(elu(Apack(512x1600) * Gt^T + bsum))
    mfma_gemm_kernel<0><<<dim3(400), 512, 0, stream>>>(
        Apack, 1600, Gt, 1600, bsum, (void*)Sb, nullptr, nullptr, 1600);
    // out[n] = b_post2
    init_out_kernel<<<dim3((NCOL + 255) / 256), 256, 0, stream>>>(b_post2, out, NCOL);
    // fused post1+post2: out[n] += sum_m w2[m]*elu(W1*Sb^T + b_post1)
    mfma_gemm_kernel<1><<<dim3(400), 512, 0, stream>>>(
        w1pack, 512, Sb, 512, b_post1, nullptr, w_post2, out, 512);
}

// Round 20
// 431.302 us; speedup vs baseline: 1.6127x; 1.2296x over previous
//
#include <hip/hip_runtime.h>
#include <hip/hip_bf16.h>

#define N_LAYERS 50
#define N_RES 32
#define N_SKIP 512
#define N_FEAT 8
#define BATCH 8
#define T_IN 8192
#define OUT_LEN 3077
#define NCOL (BATCH * OUT_LEN)   // 24616
#define N_TILES ((NCOL + 127) / 128)   // 193

typedef __bf16 bf16x8 __attribute__((ext_vector_type(8)));
typedef float  f32x4  __attribute__((ext_vector_type(4)));

// ---------------- workspace layout (bytes) ----------------
#define SZ_HP    ((size_t)BATCH * T_IN * 32 * 2)            // 4 MB per plane
#define OFF_HAH  ((size_t)0)
#define OFF_HAL  (OFF_HAH + SZ_HP)
#define OFF_HBH  (OFF_HAL + SZ_HP)
#define OFF_HBL  (OFF_HBH + SZ_HP)
#define OFF_WGH  (OFF_HBL + SZ_HP)                          // wg hi bf16 [50][64][64]
#define SZ_WG    ((size_t)50 * 64 * 64 * 2)
#define OFF_WGL  (OFF_WGH + SZ_WG)
#define OFF_WRH  (OFF_WGL + SZ_WG)                          // wr hi bf16 [50][32][32]
#define SZ_WR    ((size_t)50 * 32 * 32 * 2)
#define OFF_WRL  (OFF_WRH + SZ_WR)
#define OFF_BG   (OFF_WRL + SZ_WR)                          // bgate f32 [50][64]
#define SZ_BG    ((size_t)50 * 64 * 4)
#define OFF_AP   (OFF_BG + SZ_BG)                           // Apack bf16 [512][1600]
#define SZ_AP    ((size_t)512 * 1600 * 2)
#define OFF_W1P  (OFF_AP + SZ_AP)                           // w1pack bf16 [512][512]
#define SZ_W1P   ((size_t)512 * 512 * 2)
#define OFF_BS   (OFF_W1P + SZ_W1P)                         // bsum f32 [512]
#define SZ_BS    ((size_t)2048)
#define OFF_SB   (OFF_BS + SZ_BS)                           // Sb bf16 [NCOL][512] (elu applied)
#define SZ_SB    ((size_t)NCOL * 512 * 2)
#define OFF_GT   (OFF_SB + SZ_SB)                           // Gt bf16 [NCOL][1600]
#define SZ_GT    ((size_t)NCOL * 1600 * 2)

__device__ __forceinline__ float eluf(float v) {
    return v > 0.0f ? v : (__expf(v) - 1.0f);
}
__device__ __forceinline__ unsigned short f2bf_bits(float f) {
    __hip_bfloat16 h = __float2bfloat16(f);
    return *(unsigned short*)&h;
}
__device__ __forceinline__ float bfb2f(unsigned short u) {
    return __uint_as_float((unsigned)u << 16);
}
__device__ __forceinline__ void gl_lds16(const void* g, void* l) {
    __builtin_amdgcn_global_load_lds(
        (const __attribute__((address_space(1))) void*)g,
        (__attribute__((address_space(3))) void*)l, 16, 0, 0);
}

// ---------------- input 1x1 conv -> h0 hi/lo planes [b][t][32] ----------------
__global__ __launch_bounds__(256) void in_conv_kernel(
    const float* __restrict__ x, const float* __restrict__ w_in,
    const float* __restrict__ b_in,
    __hip_bfloat16* __restrict__ h_hi, __hip_bfloat16* __restrict__ h_lo)
{
    int tid = threadIdx.x;
    int t = blockIdx.x * 32 + (tid >> 3);
    int grp = tid & 7;
    int b = blockIdx.y;
    const float* xp = x + ((size_t)b * T_IN + t) * 8;
    float4 v0 = *(const float4*)xp;
    float4 v1 = *(const float4*)(xp + 4);
    float xv[8] = {v0.x, v0.y, v0.z, v0.w, v1.x, v1.y, v1.z, v1.w};
    ushort4 oh, ol;
    unsigned short hb[4], lb[4];
#pragma unroll
    for (int e = 0; e < 4; ++e) {
        int oc = grp * 4 + e;
        float acc = b_in[oc];
#pragma unroll
        for (int f = 0; f < 8; ++f) acc += w_in[oc * 8 + f] * xv[f];
        hb[e] = f2bf_bits(acc);
        lb[e] = f2bf_bits(acc - bfb2f(hb[e]));
    }
    oh.x = hb[0]; oh.y = hb[1]; oh.z = hb[2]; oh.w = hb[3];
    ol.x = lb[0]; ol.y = lb[1]; ol.z = lb[2]; ol.w = lb[3];
    size_t base = ((size_t)b * T_IN + t) * 32 + grp * 4;
    *(ushort4*)(h_hi + base) = oh;
    *(ushort4*)(h_lo + base) = ol;
}

// ---------------- pack weights (hi/lo where needed) ----------------
__global__ __launch_bounds__(256) void pack_kernel(
    const float* __restrict__ w_skip, const float* __restrict__ b_skip,
    const float* __restrict__ w_post1,
    const float* __restrict__ w_sig, const float* __restrict__ w_tanh,
    const float* __restrict__ w_res,
    const float* __restrict__ b_sig, const float* __restrict__ b_tanh,
    __hip_bfloat16* __restrict__ Apack, __hip_bfloat16* __restrict__ w1pack,
    __hip_bfloat16* __restrict__ wg_hi, __hip_bfloat16* __restrict__ wg_lo,
    __hip_bfloat16* __restrict__ wr_hi, __hip_bfloat16* __restrict__ wr_lo,
    float* __restrict__ bgate, float* __restrict__ bsum)
{
    int tid = blockIdx.x * 256 + threadIdx.x;    // 0 .. 819199
    {   // Apack[m][i*32+c] = bf16(w_skip[i][m][c])
        int m = tid / 1600;
        int r = tid - m * 1600;
        int i = r >> 5, c = r & 31;
        Apack[tid] = __float2bfloat16(w_skip[((size_t)i * 512 + m) * 32 + c]);
    }
    if (tid < 512 * 512) w1pack[tid] = __float2bfloat16(w_post1[tid]);
    if (tid < 50 * 64 * 64) {     // wg[l][row=2c+f][k=tap*32+ci]
        int l = tid >> 12;
        int rem = tid & 4095;
        int row = rem >> 6, k = rem & 63;
        int c = row >> 1, f = row & 1;
        int tap = k >> 5, ci = k & 31;
        const float* src = f ? w_tanh : w_sig;
        float v = src[(((size_t)l * 32 + c) * 32 + ci) * 2 + tap];
        unsigned short h = f2bf_bits(v);
        wg_hi[tid] = __float2bfloat16(v);
        wg_lo[tid] = __float2bfloat16(v - bfb2f(h));
    }
    if (tid < 50 * 1024) {
        float v = w_res[tid];
        unsigned short h = f2bf_bits(v);
        wr_hi[tid] = __float2bfloat16(v);
        wr_lo[tid] = __float2bfloat16(v - bfb2f(h));
    }
    if (tid < 50 * 64) {
        int l = tid >> 6, row = tid & 63;
        bgate[tid] = (row & 1) ? b_tanh[l * 32 + (row >> 1)] : b_sig[l * 32 + (row >> 1)];
    }
    if (tid < 512) {
        float s = 0.0f;
        for (int l = 0; l < N_LAYERS; ++l) s += b_skip[l * 512 + tid];
        bsum[tid] = s;
    }
}

// ---------------- 5 fused dilated layers, LDS-resident ----------------
// R20: gate GEMM reduced to 2-term (Wg_hi*X_hi + Wg_hi*X_lo); the Wg_lo*X_hi
// weight-rounding correction (~1e-3/layer on g) is dropped — res path stays
// 3-term. -25% MFMA, wg_lo never loaded (shorter L2 chain, -16 live VGPRs).
template <int S>
__global__ __launch_bounds__(256, 4) void group_kernel(
    const __hip_bfloat16* __restrict__ hi_in, const __hip_bfloat16* __restrict__ lo_in,
    __hip_bfloat16* __restrict__ hi_out, __hip_bfloat16* __restrict__ lo_out,
    __hip_bfloat16* __restrict__ Gt,
    const __hip_bfloat16* __restrict__ wg_hi_all,
    const __hip_bfloat16* __restrict__ wr_hi_all, const __hip_bfloat16* __restrict__ wr_lo_all,
    const float* __restrict__ bg_all, const float* __restrict__ br_all,
    int l0, int L_in, int n_ut)
{
    __shared__ __align__(16) char lds[4][128 * 80];   // {hiA, loA, hiB, loB}
    const int tid = threadIdx.x;
    const int lane = tid & 63;
    const int wave = tid >> 6;
    const int q = lane >> 4, r = lane & 15;
    const int c0 = wave * 32;

    int bid = blockIdx.x;
    int u_t = bid % n_ut;
    int rest = bid / n_ut;
    int p = rest % S;
    int b = rest / S;
    int u0 = u_t * 96;
    int u_last = (L_in - 1 - p) / S;

    // identity A-frags for residual injection: aI[i][m=r][k=8q+j] = (k == r+16i)
    bf16x8 aI[2];
    {
        union { bf16x8 v; unsigned short u[8]; } t0, t1;
#pragma unroll
        for (int e = 0; e < 8; ++e) { t0.u[e] = 0; t1.u[e] = 0; }
        int j0 = r - 8 * q;
        int j1 = r + 16 - 8 * q;
        if (j0 >= 0 && j0 < 8) t0.u[j0] = 0x3F80;
        if (j1 >= 0 && j1 < 8) t1.u[j1] = 0x3F80;
        aI[0] = t0.v; aI[1] = t1.v;
    }

    // ---- prefetch layer-0 ks=0 gate weights (in flight during staging) ----
    bf16x8 pfh[4];
#pragma unroll
    for (int i = 0; i < 4; ++i) {
        int off = (16 * i + r) * 64 + q * 8;
        pfh[i] = *(const bf16x8*)(wg_hi_all + (size_t)l0 * 4096 + off);
    }

    // ---- stage input tile: rows u0..u0+127 (clamped); lane-linear rows ----
    {
        int row = tid & 127, seg = tid >> 7;
        int u = u0 + row; if (u > u_last) u = u_last;
        size_t gb = ((size_t)b * L_in + (size_t)u * S + p) * 32 + seg * 16;
        int lb = row * 80 + seg * 32;
        uint4 a0 = *(const uint4*)(hi_in + gb);
        uint4 a1 = *(const uint4*)(hi_in + gb + 8);
        uint4 c0v = *(const uint4*)(lo_in + gb);
        uint4 c1v = *(const uint4*)(lo_in + gb + 8);
        *(uint4*)(lds[0] + lb) = a0; *(uint4*)(lds[0] + lb + 16) = a1;
        *(uint4*)(lds[1] + lb) = c0v; *(uint4*)(lds[1] + lb + 16) = c1v;
    }
    __syncthreads();

    bf16x8 gstash[5][2];   // deferred Gt payloads (registers; loop unrolled)

    int cur = 0;
#pragma unroll
    for (int l = 0; l < 5; ++l) {
        const int d = 1 << l;
        const int lg = l0 + l;
        const int L_out = L_in - S * ((2 << l) - 1);
        const int v_out = 129 - (2 << l);
        const char* xh = lds[cur];
        const char* xl = lds[cur + 1];
        char* yh = lds[2 - cur];
        char* yl = lds[3 - cur];

        const __hip_bfloat16* wg_hi = wg_hi_all + (size_t)lg * 4096;
        float4 bgv[4];
#pragma unroll
        for (int i = 0; i < 4; ++i) bgv[i] = *(const float4*)(bg_all + lg * 64 + 16 * i + 4 * q);

        // ---- gate GEMM (2-term): ks=0 uses prefetched frags; ks=1 loads inline ----
        f32x4 acc[4][2] = {};
#pragma unroll
        for (int ks = 0; ks < 2; ++ks) {
            bf16x8 afh[4];
            if (ks == 0) {
#pragma unroll
                for (int i = 0; i < 4; ++i) afh[i] = pfh[i];
            } else {
#pragma unroll
                for (int i = 0; i < 4; ++i) {
                    int off = (16 * i + r) * 64 + 32 + q * 8;
                    afh[i] = *(const bf16x8*)(wg_hi + off);
                }
            }
#pragma unroll
            for (int jj = 0; jj < 2; ++jj) {
                int cn = c0 + 16 * jj + r;
                int rowk = cn;
                if (ks) { rowk = cn + d; if (rowk > 127) rowk = 127; }
                bf16x8 bhi = *(const bf16x8*)(xh + rowk * 80 + q * 16);
                bf16x8 blo = *(const bf16x8*)(xl + rowk * 80 + q * 16);
#pragma unroll
                for (int i = 0; i < 4; ++i) {
                    acc[i][jj] = __builtin_amdgcn_mfma_f32_16x16x32_bf16(afh[i], bhi, acc[i][jj], 0, 0, 0);
                    acc[i][jj] = __builtin_amdgcn_mfma_f32_16x16x32_bf16(afh[i], blo, acc[i][jj], 0, 0, 0);
                }
            }
        }

        // ---- gates -> yh (hi only; own cols; within-wave, no barrier) ----
#pragma unroll
        for (int i = 0; i < 4; ++i) {
#pragma unroll
            for (int jj = 0; jj < 2; ++jj) {
                int cn = c0 + 16 * jj + r;
                float ps0 = acc[i][jj][0] + bgv[i].x;
                float pt0 = acc[i][jj][1] + bgv[i].y;
                float ps1 = acc[i][jj][2] + bgv[i].z;
                float pt1 = acc[i][jj][3] + bgv[i].w;
                float g0 = __builtin_amdgcn_rcpf(1.0f + __expf(-ps0)) *
                           (1.0f - 2.0f * __builtin_amdgcn_rcpf(__expf(2.0f * pt0) + 1.0f));
                float g1 = __builtin_amdgcn_rcpf(1.0f + __expf(-ps1)) *
                           (1.0f - 2.0f * __builtin_amdgcn_rcpf(__expf(2.0f * pt1) + 1.0f));
                *(unsigned int*)(yh + cn * 80 + 16 * i + 4 * q) =
                    (unsigned)f2bf_bits(g0) | ((unsigned)f2bf_bits(g1) << 16);
            }
        }
        // no barrier: g is read back by the same wave only (lgkmcnt ordering)

        // ---- res GEMM (Wr_h*g + Wr_l*g + I*x1_hi + I*x1_lo); stash g for deferred Gt ----
        const __hip_bfloat16* wr_hi = wr_hi_all + (size_t)lg * 1024;
        const __hip_bfloat16* wr_lo = wr_lo_all + (size_t)lg * 1024;
        bf16x8 arh[2], arl[2];
#pragma unroll
        for (int i = 0; i < 2; ++i) {
            int off = (16 * i + r) * 32 + q * 8;
            arh[i] = *(const bf16x8*)(wr_hi + off);
            arl[i] = *(const bf16x8*)(wr_lo + off);
        }
        f32x4 racc[2][2] = {};
#pragma unroll
        for (int jj = 0; jj < 2; ++jj) {
            int cn = c0 + 16 * jj + r;
            bf16x8 ghi = *(const bf16x8*)(yh + cn * 80 + q * 16);
            gstash[l][jj] = ghi;
            int r1 = cn + d; if (r1 > 127) r1 = 127;
            bf16x8 x1h = *(const bf16x8*)(xh + r1 * 80 + q * 16);
            bf16x8 x1l = *(const bf16x8*)(xl + r1 * 80 + q * 16);
#pragma unroll
            for (int i = 0; i < 2; ++i) {
                racc[i][jj] = __builtin_amdgcn_mfma_f32_16x16x32_bf16(arh[i], ghi, racc[i][jj], 0, 0, 0);
                racc[i][jj] = __builtin_amdgcn_mfma_f32_16x16x32_bf16(arl[i], ghi, racc[i][jj], 0, 0, 0);
                racc[i][jj] = __builtin_amdgcn_mfma_f32_16x16x32_bf16(aI[i], x1h, racc[i][jj], 0, 0, 0);
                racc[i][jj] = __builtin_amdgcn_mfma_f32_16x16x32_bf16(aI[i], x1l, racc[i][jj], 0, 0, 0);
            }
        }
        // no barrier: rows about to be overwritten belong to this wave only

        // ---- h_out (racc includes residual), RNE hi/lo ----
#pragma unroll
        for (int jj = 0; jj < 2; ++jj) {
            int cn = c0 + 16 * jj + r;
            int t = (u0 + cn) * S + p;
            bool wr_global = (l == 4) && (cn < v_out) && (t < L_out);
#pragma unroll
            for (int i = 0; i < 2; ++i) {
                int ch = 16 * i + 4 * q;
                float4 bb = *(const float4*)(br_all + lg * 32 + ch);
                float o0 = racc[i][jj][0] + bb.x;
                float o1 = racc[i][jj][1] + bb.y;
                float o2 = racc[i][jj][2] + bb.z;
                float o3 = racc[i][jj][3] + bb.w;
                ushort4 oh, ol;
                oh.x = f2bf_bits(o0); ol.x = f2bf_bits(o0 - bfb2f(oh.x));
                oh.y = f2bf_bits(o1); ol.y = f2bf_bits(o1 - bfb2f(oh.y));
                oh.z = f2bf_bits(o2); ol.z = f2bf_bits(o2 - bfb2f(oh.z));
                oh.w = f2bf_bits(o3); ol.w = f2bf_bits(o3 - bfb2f(oh.w));
                if (l == 4) {
                    if (wr_global) {
                        size_t base = ((size_t)b * L_out + t) * 32 + ch;
                        *(ushort4*)(hi_out + base) = oh;
                        *(ushort4*)(lo_out + base) = ol;
                    }
                } else {
                    int off = cn * 80 + ch * 2;
                    *(ushort4*)(yh + off) = oh;
                    *(ushort4*)(yl + off) = ol;
                }
            }
        }
        if (l < 4) {
            // prefetch next layer's ks=0 gate weights BEFORE the barrier
#pragma unroll
            for (int i = 0; i < 4; ++i) {
                int off = (16 * i + r) * 64 + q * 8;
                pfh[i] = *(const bf16x8*)(wg_hi_all + (size_t)(lg + 1) * 4096 + off);
            }
            __syncthreads();   // h visible to other waves' taps (no vmem stores pending)
        }
        cur = 2 - cur;
    }

    // ---- deferred Gt flush (after all barriers; drains once at kernel end) ----
#pragma unroll
    for (int l = 0; l < 5; ++l) {
        const int lg = l0 + l;
        const int L_out_l = L_in - S * ((2 << l) - 1);
        const int v_out_l = 129 - (2 << l);
        const int ws_l = L_out_l - OUT_LEN;
#pragma unroll
        for (int jj = 0; jj < 2; ++jj) {
            int cn = c0 + 16 * jj + r;
            int t = (u0 + cn) * S + p;
            if (cn < v_out_l && t >= ws_l && t < L_out_l) {
                size_t n = (size_t)b * OUT_LEN + (t - ws_l);
                *(bf16x8*)(Gt + n * 1600 + (size_t)lg * 32 + q * 8) = gstash[l][jj];
            }
        }
    }
}

// ---------------- MFMA GEMM, 256m x 128n tile, 512 thr (R17 proven form) ----------------
// MODE 0: skip  -> Sb bf16 [n][512] = bf16(elu(acc+bias))
// MODE 1: post1+post2 fused -> out[n] += sum_m w2[m]*elu(acc+bias[m])  (f32 atomics)
template <int MODE>
__global__ __launch_bounds__(512) void mfma_gemm_kernel(
    const __hip_bfloat16* __restrict__ A, int lda,
    const __hip_bfloat16* __restrict__ B, int ldb,
    const float* __restrict__ bias, void* __restrict__ Cout,
    const float* __restrict__ w2, float* __restrict__ outp, int K)
{
    int id = blockIdx.x;
    int j = id >> 3;
    int m0 = (j & 1) * 256;
    int nt = (id & 7) + 8 * (j >> 1);
    if (nt >= N_TILES) return;
    int n0 = nt * 128;

    __shared__ __align__(16) char As[256 * 128];   // 32 KB
    __shared__ __align__(16) char Bs[128 * 128];   // 16 KB
    int tid = threadIdx.x;
    int lane = tid & 63, wave = tid >> 6;
    int wm = (wave & 3) * 64, wn = (wave >> 2) * 64;
    int q = lane >> 4, r = lane & 15;

    f32x4 acc[4][4] = {};

    for (int k0 = 0; k0 < K; k0 += 64) {
        __syncthreads();
#pragma unroll
        for (int i = 0; i < 4; ++i) {          // A: 2048 16B-slots
            int li = i * 512 + tid;
            int row = li >> 3, ch = li & 7;
            int cs = (ch ^ (row & 7)) * 8;
            gl_lds16(A + (size_t)(m0 + row) * lda + k0 + cs, As + li * 16);
        }
#pragma unroll
        for (int i = 0; i < 2; ++i) {          // B: 1024 16B-slots
            int li = i * 512 + tid;
            int row = li >> 3, ch = li & 7;
            int cs = (ch ^ (row & 7)) * 8;
            int gn = n0 + row; if (gn > NCOL - 1) gn = NCOL - 1;
            gl_lds16(B + (size_t)gn * ldb + k0 + cs, Bs + li * 16);
        }
        __syncthreads();
#pragma unroll
        for (int ks = 0; ks < 2; ++ks) {
            bf16x8 af[4], bfr[4];
#pragma unroll
            for (int s = 0; s < 4; ++s) {
                int m = wm + s * 16 + r;
                int cg = ks * 4 + q;
                af[s]  = *(const bf16x8*)(As + m * 128 + ((cg ^ (m & 7)) * 16));
                int n = wn + s * 16 + r;
                bfr[s] = *(const bf16x8*)(Bs + n * 128 + ((cg ^ (n & 7)) * 16));
            }
#pragma unroll
            for (int i = 0; i < 4; ++i)
#pragma unroll
                for (int jx = 0; jx < 4; ++jx)
                    acc[i][jx] = __builtin_amdgcn_mfma_f32_16x16x32_bf16(
                        af[i], bfr[jx], acc[i][jx], 0, 0, 0);
        }
    }

    if (MODE == 0) {
        __hip_bfloat16* Sb = (__hip_bfloat16*)Cout;
#pragma unroll
        for (int jx = 0; jx < 4; ++jx) {
            int n = n0 + wn + jx * 16 + r;
            if (n >= NCOL) continue;
#pragma unroll
            for (int i = 0; i < 4; ++i) {
                int mb = m0 + wm + i * 16 + q * 4;
                float4 bs = *(const float4*)(bias + mb);
                ushort4 u;
                u.x = f2bf_bits(eluf(acc[i][jx][0] + bs.x));
                u.y = f2bf_bits(eluf(acc[i][jx][1] + bs.y));
                u.z = f2bf_bits(eluf(acc[i][jx][2] + bs.z));
                u.w = f2bf_bits(eluf(acc[i][jx][3] + bs.w));
                *(ushort4*)(Sb + (size_t)n * 512 + mb) = u;
            }
        }
    } else {
        // fused post1+post2: out[n] += sum_m w2[m]*elu(y1[m][n])
        float part[4] = {0.0f, 0.0f, 0.0f, 0.0f};
#pragma unroll
        for (int i = 0; i < 4; ++i) {
            int mb = m0 + wm + i * 16 + q * 4;
            float4 bs = *(const float4*)(bias + mb);
            float4 wv = *(const float4*)(w2 + mb);
#pragma unroll
            for (int jx = 0; jx < 4; ++jx) {
                part[jx] += wv.x * eluf(acc[i][jx][0] + bs.x);
                part[jx] += wv.y * eluf(acc[i][jx][1] + bs.y);
                part[jx] += wv.z * eluf(acc[i][jx][2] + bs.z);
                part[jx] += wv.w * eluf(acc[i][jx][3] + bs.w);
            }
        }
#pragma unroll
        for (int jx = 0; jx < 4; ++jx) {
            float v = part[jx];
            v += __shfl_xor(v, 16, 64);
            v += __shfl_xor(v, 32, 64);
            int n = n0 + wn + jx * 16 + r;
            if (q == 0 && n < NCOL) atomicAdd(outp + n, v);
        }
    }
}

// ---------------- out init: out[n] = b_post2 (d_out is re-poisoned each replay) ----------------
__global__ __launch_bounds__(256) void init_out_kernel(
    const float* __restrict__ b2, float* __restrict__ out, int N)
{
    int n = blockIdx.x * 256 + threadIdx.x;
    if (n < N) out[n] = b2[0];
}

extern "C" void kernel_launch(void* const* d_in, const int* in_sizes, int n_in,
                              void* d_out, int out_size, void* d_ws, size_t ws_size,
                              hipStream_t stream)
{
    const float* x      = (const float*)d_in[0];
    const float* w_in   = (const float*)d_in[1];
    const float* b_in   = (const float*)d_in[2];
    const float* w_sig  = (const float*)d_in[3];
    const float* b_sig  = (const float*)d_in[4];
    const float* w_tanh = (const float*)d_in[5];
    const float* b_tanh = (const float*)d_in[6];
    const float* w_skip = (const float*)d_in[7];
    const float* b_skip = (const float*)d_in[8];
    const float* w_res  = (const float*)d_in[9];
    const float* b_res  = (const float*)d_in[10];
    const float* w_post1 = (const float*)d_in[11];
    const float* b_post1 = (const float*)d_in[12];
    const float* w_post2 = (const float*)d_in[13];
    const float* b_post2 = (const float*)d_in[14];
    float* out = (float*)d_out;

    char* ws = (char*)d_ws;
    __hip_bfloat16* hAh = (__hip_bfloat16*)(ws + OFF_HAH);
    __hip_bfloat16* hAl = (__hip_bfloat16*)(ws + OFF_HAL);
    __hip_bfloat16* hBh = (__hip_bfloat16*)(ws + OFF_HBH);
    __hip_bfloat16* hBl = (__hip_bfloat16*)(ws + OFF_HBL);
    __hip_bfloat16* wgh = (__hip_bfloat16*)(ws + OFF_WGH);
    __hip_bfloat16* wgl = (__hip_bfloat16*)(ws + OFF_WGL);
    __hip_bfloat16* wrh = (__hip_bfloat16*)(ws + OFF_WRH);
    __hip_bfloat16* wrl = (__hip_bfloat16*)(ws + OFF_WRL);
    float* bgate = (float*)(ws + OFF_BG);
    __hip_bfloat16* Apack  = (__hip_bfloat16*)(ws + OFF_AP);
    __hip_bfloat16* w1pack = (__hip_bfloat16*)(ws + OFF_W1P);
    float* bsum = (float*)(ws + OFF_BS);
    __hip_bfloat16* Sb = (__hip_bfloat16*)(ws + OFF_SB);
    __hip_bfloat16* Gt = (__hip_bfloat16*)(ws + OFF_GT);

    in_conv_kernel<<<dim3(T_IN / 32, BATCH), 256, 0, stream>>>(x, w_in, b_in, hAh, hAl);
    pack_kernel<<<dim3(512 * 1600 / 256), 256, 0, stream>>>(
        w_skip, b_skip, w_post1, w_sig, w_tanh, w_res, b_sig, b_tanh,
        Apack, w1pack, wgh, wgl, wrh, wrl, bgate, bsum);

    int L = T_IN;
    __hip_bfloat16 *cih = hAh, *cil = hAl, *coh = hBh, *col_ = hBl;
    for (int rep = 0; rep < 5; ++rep) {
        {   // group A: layers rep*10 .. +4, d=1..16 (S=1)
            int out_len = L - 31;
            int n_ut = (out_len + 95) / 96;
            group_kernel<1><<<dim3(BATCH * n_ut), 256, 0, stream>>>(
                cih, cil, coh, col_, Gt, wgh, wrh, wrl, bgate, b_res,
                rep * 10, L, n_ut);
            L = out_len;
            __hip_bfloat16* t1 = cih; cih = coh; coh = t1;
            __hip_bfloat16* t2 = cil; cil = col_; col_ = t2;
        }
        {   // group B: layers rep*10+5 .. +9, d=32..512 (S=32 polyphase)
            int U = (L + 31) / 32;
            int out_u = U - 31; if (out_u < 1) out_u = 1;
            int n_ut = (out_u + 95) / 96;
            group_kernel<32><<<dim3(BATCH * 32 * n_ut), 256, 0, stream>>>(
                cih, cil, coh, col_, Gt, wgh, wrh, wrl, bgate, b_res,
                rep * 10 + 5, L, n_ut);
            L = L - 992;
            __hip_bfloat16* t1 = cih; cih = coh; coh = t1;
            __hip_bfloat16* t2 = cil; cil = col_; col_ = t2;
        }
    }

    // skip GEMM: Sb[n][512] = bf16(elu(Apack(512x1600) * Gt^T + bsum))
    mfma_gemm_kernel<0><<<dim3(400), 512, 0, stream>>>(
        Apack, 1600, Gt, 1600, bsum, (void*)Sb, nullptr, nullptr, 1600);
    // out[n] = b_post2
    init_out_kernel<<<dim3((NCOL + 255) / 256), 256, 0, stream>>>(b_post2, out, NCOL);
    // fused post1+post2: out[n] += sum_m w2[m]*elu(W1*Sb^T + b_post1)
    mfma_gemm_kernel<1><<<dim3(400), 512, 0, stream>>>(
        w1pack, 512, Sb, 512, b_post1, nullptr, w_post2, out, 512);
}

// Round 21
// 420.965 us; speedup vs baseline: 1.6523x; 1.0246x over previous
//
#include <hip/hip_runtime.h>
#include <hip/hip_bf16.h>

#define N_LAYERS 50
#define N_RES 32
#define N_SKIP 512
#define N_FEAT 8
#define BATCH 8
#define T_IN 8192
#define OUT_LEN 3077
#define NCOL (BATCH * OUT_LEN)   // 24616
#define N_TILES ((NCOL + 127) / 128)   // 193

typedef __bf16 bf16x8 __attribute__((ext_vector_type(8)));
typedef float  f32x4  __attribute__((ext_vector_type(4)));

// ---------------- workspace layout (bytes) ----------------
#define SZ_HP    ((size_t)BATCH * T_IN * 32 * 2)            // 4 MB per plane
#define OFF_HAH  ((size_t)0)
#define OFF_HAL  (OFF_HAH + SZ_HP)
#define OFF_HBH  (OFF_HAL + SZ_HP)
#define OFF_HBL  (OFF_HBH + SZ_HP)
#define OFF_WGH  (OFF_HBL + SZ_HP)                          // wg hi bf16 [50][64][64]
#define SZ_WG    ((size_t)50 * 64 * 64 * 2)
#define OFF_WGL  (OFF_WGH + SZ_WG)
#define OFF_WRH  (OFF_WGL + SZ_WG)                          // wr hi bf16 [50][32][32]
#define SZ_WR    ((size_t)50 * 32 * 32 * 2)
#define OFF_WRL  (OFF_WRH + SZ_WR)
#define OFF_BG   (OFF_WRL + SZ_WR)                          // bgate f32 [50][64]
#define SZ_BG    ((size_t)50 * 64 * 4)
#define OFF_AP   (OFF_BG + SZ_BG)                           // Apack bf16 [512][1600]
#define SZ_AP    ((size_t)512 * 1600 * 2)
#define OFF_W1P  (OFF_AP + SZ_AP)                           // w1pack bf16 [512][512]
#define SZ_W1P   ((size_t)512 * 512 * 2)
#define OFF_BS   (OFF_W1P + SZ_W1P)                         // bsum f32 [512]
#define SZ_BS    ((size_t)2048)
#define OFF_SB   (OFF_BS + SZ_BS)                           // Sb bf16 [NCOL][512] (elu applied)
#define SZ_SB    ((size_t)NCOL * 512 * 2)
#define OFF_GT   (OFF_SB + SZ_SB)                           // Gt bf16 [NCOL][1600]
#define SZ_GT    ((size_t)NCOL * 1600 * 2)

__device__ __forceinline__ float eluf(float v) {
    return v > 0.0f ? v : (__expf(v) - 1.0f);
}
__device__ __forceinline__ unsigned short f2bf_bits(float f) {
    __hip_bfloat16 h = __float2bfloat16(f);
    return *(unsigned short*)&h;
}
__device__ __forceinline__ float bfb2f(unsigned short u) {
    return __uint_as_float((unsigned)u << 16);
}
__device__ __forceinline__ void gl_lds16(const void* g, void* l) {
    __builtin_amdgcn_global_load_lds(
        (const __attribute__((address_space(1))) void*)g,
        (__attribute__((address_space(3))) void*)l, 16, 0, 0);
}

// ---------------- input 1x1 conv -> h0 hi/lo planes [b][t][32] ----------------
__global__ __launch_bounds__(256) void in_conv_kernel(
    const float* __restrict__ x, const float* __restrict__ w_in,
    const float* __restrict__ b_in,
    __hip_bfloat16* __restrict__ h_hi, __hip_bfloat16* __restrict__ h_lo)
{
    int tid = threadIdx.x;
    int t = blockIdx.x * 32 + (tid >> 3);
    int grp = tid & 7;
    int b = blockIdx.y;
    const float* xp = x + ((size_t)b * T_IN + t) * 8;
    float4 v0 = *(const float4*)xp;
    float4 v1 = *(const float4*)(xp + 4);
    float xv[8] = {v0.x, v0.y, v0.z, v0.w, v1.x, v1.y, v1.z, v1.w};
    ushort4 oh, ol;
    unsigned short hb[4], lb[4];
#pragma unroll
    for (int e = 0; e < 4; ++e) {
        int oc = grp * 4 + e;
        float acc = b_in[oc];
#pragma unroll
        for (int f = 0; f < 8; ++f) acc += w_in[oc * 8 + f] * xv[f];
        hb[e] = f2bf_bits(acc);
        lb[e] = f2bf_bits(acc - bfb2f(hb[e]));
    }
    oh.x = hb[0]; oh.y = hb[1]; oh.z = hb[2]; oh.w = hb[3];
    ol.x = lb[0]; ol.y = lb[1]; ol.z = lb[2]; ol.w = lb[3];
    size_t base = ((size_t)b * T_IN + t) * 32 + grp * 4;
    *(ushort4*)(h_hi + base) = oh;
    *(ushort4*)(h_lo + base) = ol;
}

// ---------------- pack weights (hi/lo where needed) ----------------
__global__ __launch_bounds__(256) void pack_kernel(
    const float* __restrict__ w_skip, const float* __restrict__ b_skip,
    const float* __restrict__ w_post1,
    const float* __restrict__ w_sig, const float* __restrict__ w_tanh,
    const float* __restrict__ w_res,
    const float* __restrict__ b_sig, const float* __restrict__ b_tanh,
    __hip_bfloat16* __restrict__ Apack, __hip_bfloat16* __restrict__ w1pack,
    __hip_bfloat16* __restrict__ wg_hi, __hip_bfloat16* __restrict__ wg_lo,
    __hip_bfloat16* __restrict__ wr_hi, __hip_bfloat16* __restrict__ wr_lo,
    float* __restrict__ bgate, float* __restrict__ bsum)
{
    int tid = blockIdx.x * 256 + threadIdx.x;    // 0 .. 819199
    {   // Apack[m][i*32+c] = bf16(w_skip[i][m][c])
        int m = tid / 1600;
        int r = tid - m * 1600;
        int i = r >> 5, c = r & 31;
        Apack[tid] = __float2bfloat16(w_skip[((size_t)i * 512 + m) * 32 + c]);
    }
    if (tid < 512 * 512) w1pack[tid] = __float2bfloat16(w_post1[tid]);
    if (tid < 50 * 64 * 64) {     // wg[l][row=2c+f][k=tap*32+ci]
        int l = tid >> 12;
        int rem = tid & 4095;
        int row = rem >> 6, k = rem & 63;
        int c = row >> 1, f = row & 1;
        int tap = k >> 5, ci = k & 31;
        const float* src = f ? w_tanh : w_sig;
        float v = src[(((size_t)l * 32 + c) * 32 + ci) * 2 + tap];
        unsigned short h = f2bf_bits(v);
        wg_hi[tid] = __float2bfloat16(v);
        wg_lo[tid] = __float2bfloat16(v - bfb2f(h));
    }
    if (tid < 50 * 1024) {
        float v = w_res[tid];
        unsigned short h = f2bf_bits(v);
        wr_hi[tid] = __float2bfloat16(v);
        wr_lo[tid] = __float2bfloat16(v - bfb2f(h));
    }
    if (tid < 50 * 64) {
        int l = tid >> 6, row = tid & 63;
        bgate[tid] = (row & 1) ? b_tanh[l * 32 + (row >> 1)] : b_sig[l * 32 + (row >> 1)];
    }
    if (tid < 512) {
        float s = 0.0f;
        for (int l = 0; l < N_LAYERS; ++l) s += b_skip[l * 512 + tid];
        bsum[tid] = s;
    }
}

// ---------------- 5 fused dilated layers, LDS-resident ----------------
// R21: FULL gate-weight prefetch (both k-halves, 8 frags = 32 VGPR) for layer
// l+1 issued before layer l's barrier — R20 left the ks=1 half loading after
// the barrier on the critical path. Gate stays 2-term; res stays 3-term.
template <int S>
__global__ __launch_bounds__(256, 4) void group_kernel(
    const __hip_bfloat16* __restrict__ hi_in, const __hip_bfloat16* __restrict__ lo_in,
    __hip_bfloat16* __restrict__ hi_out, __hip_bfloat16* __restrict__ lo_out,
    __hip_bfloat16* __restrict__ Gt,
    const __hip_bfloat16* __restrict__ wg_hi_all,
    const __hip_bfloat16* __restrict__ wr_hi_all, const __hip_bfloat16* __restrict__ wr_lo_all,
    const float* __restrict__ bg_all, const float* __restrict__ br_all,
    int l0, int L_in, int n_ut)
{
    __shared__ __align__(16) char lds[4][128 * 80];   // {hiA, loA, hiB, loB}
    const int tid = threadIdx.x;
    const int lane = tid & 63;
    const int wave = tid >> 6;
    const int q = lane >> 4, r = lane & 15;
    const int c0 = wave * 32;

    int bid = blockIdx.x;
    int u_t = bid % n_ut;
    int rest = bid / n_ut;
    int p = rest % S;
    int b = rest / S;
    int u0 = u_t * 96;
    int u_last = (L_in - 1 - p) / S;

    // identity A-frags for residual injection: aI[i][m=r][k=8q+j] = (k == r+16i)
    bf16x8 aI[2];
    {
        union { bf16x8 v; unsigned short u[8]; } t0, t1;
#pragma unroll
        for (int e = 0; e < 8; ++e) { t0.u[e] = 0; t1.u[e] = 0; }
        int j0 = r - 8 * q;
        int j1 = r + 16 - 8 * q;
        if (j0 >= 0 && j0 < 8) t0.u[j0] = 0x3F80;
        if (j1 >= 0 && j1 < 8) t1.u[j1] = 0x3F80;
        aI[0] = t0.v; aI[1] = t1.v;
    }

    // ---- prefetch layer-0 gate weights, BOTH k-halves (in flight during staging) ----
    bf16x8 pfh[8];
#pragma unroll
    for (int i = 0; i < 8; ++i) {
        int off = (16 * (i & 3) + r) * 64 + (i >> 2) * 32 + q * 8;
        pfh[i] = *(const bf16x8*)(wg_hi_all + (size_t)l0 * 4096 + off);
    }

    // ---- stage input tile: rows u0..u0+127 (clamped); lane-linear rows ----
    {
        int row = tid & 127, seg = tid >> 7;
        int u = u0 + row; if (u > u_last) u = u_last;
        size_t gb = ((size_t)b * L_in + (size_t)u * S + p) * 32 + seg * 16;
        int lb = row * 80 + seg * 32;
        uint4 a0 = *(const uint4*)(hi_in + gb);
        uint4 a1 = *(const uint4*)(hi_in + gb + 8);
        uint4 c0v = *(const uint4*)(lo_in + gb);
        uint4 c1v = *(const uint4*)(lo_in + gb + 8);
        *(uint4*)(lds[0] + lb) = a0; *(uint4*)(lds[0] + lb + 16) = a1;
        *(uint4*)(lds[1] + lb) = c0v; *(uint4*)(lds[1] + lb + 16) = c1v;
    }
    __syncthreads();

    bf16x8 gstash[5][2];   // deferred Gt payloads (registers; loop unrolled)

    int cur = 0;
#pragma unroll
    for (int l = 0; l < 5; ++l) {
        const int d = 1 << l;
        const int lg = l0 + l;
        const int L_out = L_in - S * ((2 << l) - 1);
        const int v_out = 129 - (2 << l);
        const char* xh = lds[cur];
        const char* xl = lds[cur + 1];
        char* yh = lds[2 - cur];
        char* yl = lds[3 - cur];

        float4 bgv[4];
#pragma unroll
        for (int i = 0; i < 4; ++i) bgv[i] = *(const float4*)(bg_all + lg * 64 + 16 * i + 4 * q);

        // ---- gate GEMM (2-term), all weights from prefetch regs ----
        f32x4 acc[4][2] = {};
#pragma unroll
        for (int ks = 0; ks < 2; ++ks) {
#pragma unroll
            for (int jj = 0; jj < 2; ++jj) {
                int cn = c0 + 16 * jj + r;
                int rowk = cn;
                if (ks) { rowk = cn + d; if (rowk > 127) rowk = 127; }
                bf16x8 bhi = *(const bf16x8*)(xh + rowk * 80 + q * 16);
                bf16x8 blo = *(const bf16x8*)(xl + rowk * 80 + q * 16);
#pragma unroll
                for (int i = 0; i < 4; ++i) {
                    acc[i][jj] = __builtin_amdgcn_mfma_f32_16x16x32_bf16(pfh[ks * 4 + i], bhi, acc[i][jj], 0, 0, 0);
                    acc[i][jj] = __builtin_amdgcn_mfma_f32_16x16x32_bf16(pfh[ks * 4 + i], blo, acc[i][jj], 0, 0, 0);
                }
            }
        }

        // ---- gates -> yh (hi only; own cols; within-wave, no barrier) ----
#pragma unroll
        for (int i = 0; i < 4; ++i) {
#pragma unroll
            for (int jj = 0; jj < 2; ++jj) {
                int cn = c0 + 16 * jj + r;
                float ps0 = acc[i][jj][0] + bgv[i].x;
                float pt0 = acc[i][jj][1] + bgv[i].y;
                float ps1 = acc[i][jj][2] + bgv[i].z;
                float pt1 = acc[i][jj][3] + bgv[i].w;
                float g0 = __builtin_amdgcn_rcpf(1.0f + __expf(-ps0)) *
                           (1.0f - 2.0f * __builtin_amdgcn_rcpf(__expf(2.0f * pt0) + 1.0f));
                float g1 = __builtin_amdgcn_rcpf(1.0f + __expf(-ps1)) *
                           (1.0f - 2.0f * __builtin_amdgcn_rcpf(__expf(2.0f * pt1) + 1.0f));
                *(unsigned int*)(yh + cn * 80 + 16 * i + 4 * q) =
                    (unsigned)f2bf_bits(g0) | ((unsigned)f2bf_bits(g1) << 16);
            }
        }
        // no barrier: g is read back by the same wave only (lgkmcnt ordering)

        // ---- res GEMM (Wr_h*g + Wr_l*g + I*x1_hi + I*x1_lo); stash g for deferred Gt ----
        const __hip_bfloat16* wr_hi = wr_hi_all + (size_t)lg * 1024;
        const __hip_bfloat16* wr_lo = wr_lo_all + (size_t)lg * 1024;
        bf16x8 arh[2], arl[2];
#pragma unroll
        for (int i = 0; i < 2; ++i) {
            int off = (16 * i + r) * 32 + q * 8;
            arh[i] = *(const bf16x8*)(wr_hi + off);
            arl[i] = *(const bf16x8*)(wr_lo + off);
        }
        f32x4 racc[2][2] = {};
#pragma unroll
        for (int jj = 0; jj < 2; ++jj) {
            int cn = c0 + 16 * jj + r;
            bf16x8 ghi = *(const bf16x8*)(yh + cn * 80 + q * 16);
            gstash[l][jj] = ghi;
            int r1 = cn + d; if (r1 > 127) r1 = 127;
            bf16x8 x1h = *(const bf16x8*)(xh + r1 * 80 + q * 16);
            bf16x8 x1l = *(const bf16x8*)(xl + r1 * 80 + q * 16);
#pragma unroll
            for (int i = 0; i < 2; ++i) {
                racc[i][jj] = __builtin_amdgcn_mfma_f32_16x16x32_bf16(arh[i], ghi, racc[i][jj], 0, 0, 0);
                racc[i][jj] = __builtin_amdgcn_mfma_f32_16x16x32_bf16(arl[i], ghi, racc[i][jj], 0, 0, 0);
                racc[i][jj] = __builtin_amdgcn_mfma_f32_16x16x32_bf16(aI[i], x1h, racc[i][jj], 0, 0, 0);
                racc[i][jj] = __builtin_amdgcn_mfma_f32_16x16x32_bf16(aI[i], x1l, racc[i][jj], 0, 0, 0);
            }
        }
        // no barrier: rows about to be overwritten belong to this wave only

        // ---- h_out (racc includes residual), RNE hi/lo ----
#pragma unroll
        for (int jj = 0; jj < 2; ++jj) {
            int cn = c0 + 16 * jj + r;
            int t = (u0 + cn) * S + p;
            bool wr_global = (l == 4) && (cn < v_out) && (t < L_out);
#pragma unroll
            for (int i = 0; i < 2; ++i) {
                int ch = 16 * i + 4 * q;
                float4 bb = *(const float4*)(br_all + lg * 32 + ch);
                float o0 = racc[i][jj][0] + bb.x;
                float o1 = racc[i][jj][1] + bb.y;
                float o2 = racc[i][jj][2] + bb.z;
                float o3 = racc[i][jj][3] + bb.w;
                ushort4 oh, ol;
                oh.x = f2bf_bits(o0); ol.x = f2bf_bits(o0 - bfb2f(oh.x));
                oh.y = f2bf_bits(o1); ol.y = f2bf_bits(o1 - bfb2f(oh.y));
                oh.z = f2bf_bits(o2); ol.z = f2bf_bits(o2 - bfb2f(oh.z));
                oh.w = f2bf_bits(o3); ol.w = f2bf_bits(o3 - bfb2f(oh.w));
                if (l == 4) {
                    if (wr_global) {
                        size_t base = ((size_t)b * L_out + t) * 32 + ch;
                        *(ushort4*)(hi_out + base) = oh;
                        *(ushort4*)(lo_out + base) = ol;
                    }
                } else {
                    int off = cn * 80 + ch * 2;
                    *(ushort4*)(yh + off) = oh;
                    *(ushort4*)(yl + off) = ol;
                }
            }
        }
        if (l < 4) {
            // prefetch next layer's FULL gate weight set BEFORE the barrier
#pragma unroll
            for (int i = 0; i < 8; ++i) {
                int off = (16 * (i & 3) + r) * 64 + (i >> 2) * 32 + q * 8;
                pfh[i] = *(const bf16x8*)(wg_hi_all + (size_t)(lg + 1) * 4096 + off);
            }
            __syncthreads();   // h visible to other waves' taps (no vmem stores pending)
        }
        cur = 2 - cur;
    }

    // ---- deferred Gt flush (after all barriers; drains once at kernel end) ----
#pragma unroll
    for (int l = 0; l < 5; ++l) {
        const int lg = l0 + l;
        const int L_out_l = L_in - S * ((2 << l) - 1);
        const int v_out_l = 129 - (2 << l);
        const int ws_l = L_out_l - OUT_LEN;
#pragma unroll
        for (int jj = 0; jj < 2; ++jj) {
            int cn = c0 + 16 * jj + r;
            int t = (u0 + cn) * S + p;
            if (cn < v_out_l && t >= ws_l && t < L_out_l) {
                size_t n = (size_t)b * OUT_LEN + (t - ws_l);
                *(bf16x8*)(Gt + n * 1600 + (size_t)lg * 32 + q * 8) = gstash[l][jj];
            }
        }
    }
}

// ---------------- MFMA GEMM, 256m x 128n tile, 512 thr (R17 proven form) ----------------
// MODE 0: skip  -> Sb bf16 [n][512] = bf16(elu(acc+bias))
// MODE 1: post1+post2 fused -> out[n] += sum_m w2[m]*elu(acc+bias[m])  (f32 atomics)
template <int MODE>
__global__ __launch_bounds__(512) void mfma_gemm_kernel(
    const __hip_bfloat16* __restrict__ A, int lda,
    const __hip_bfloat16* __restrict__ B, int ldb,
    const float* __restrict__ bias, void* __restrict__ Cout,
    const float* __restrict__ w2, float* __restrict__ outp, int K)
{
    int id = blockIdx.x;
    int j = id >> 3;
    int m0 = (j & 1) * 256;
    int nt = (id & 7) + 8 * (j >> 1);
    if (nt >= N_TILES) return;
    int n0 = nt * 128;

    __shared__ __align__(16) char As[256 * 128];   // 32 KB
    __shared__ __align__(16) char Bs[128 * 128];   // 16 KB
    int tid = threadIdx.x;
    int lane = tid & 63, wave = tid >> 6;
    int wm = (wave & 3) * 64, wn = (wave >> 2) * 64;
    int q = lane >> 4, r = lane & 15;

    f32x4 acc[4][4] = {};

    for (int k0 = 0; k0 < K; k0 += 64) {
        __syncthreads();
#pragma unroll
        for (int i = 0; i < 4; ++i) {          // A: 2048 16B-slots
            int li = i * 512 + tid;
            int row = li >> 3, ch = li & 7;
            int cs = (ch ^ (row & 7)) * 8;
            gl_lds16(A + (size_t)(m0 + row) * lda + k0 + cs, As + li * 16);
        }
#pragma unroll
        for (int i = 0; i < 2; ++i) {          // B: 1024 16B-slots
            int li = i * 512 + tid;
            int row = li >> 3, ch = li & 7;
            int cs = (ch ^ (row & 7)) * 8;
            int gn = n0 + row; if (gn > NCOL - 1) gn = NCOL - 1;
            gl_lds16(B + (size_t)gn * ldb + k0 + cs, Bs + li * 16);
        }
        __syncthreads();
#pragma unroll
        for (int ks = 0; ks < 2; ++ks) {
            bf16x8 af[4], bfr[4];
#pragma unroll
            for (int s = 0; s < 4; ++s) {
                int m = wm + s * 16 + r;
                int cg = ks * 4 + q;
                af[s]  = *(const bf16x8*)(As + m * 128 + ((cg ^ (m & 7)) * 16));
                int n = wn + s * 16 + r;
                bfr[s] = *(const bf16x8*)(Bs + n * 128 + ((cg ^ (n & 7)) * 16));
            }
#pragma unroll
            for (int i = 0; i < 4; ++i)
#pragma unroll
                for (int jx = 0; jx < 4; ++jx)
                    acc[i][jx] = __builtin_amdgcn_mfma_f32_16x16x32_bf16(
                        af[i], bfr[jx], acc[i][jx], 0, 0, 0);
        }
    }

    if (MODE == 0) {
        __hip_bfloat16* Sb = (__hip_bfloat16*)Cout;
#pragma unroll
        for (int jx = 0; jx < 4; ++jx) {
            int n = n0 + wn + jx * 16 + r;
            if (n >= NCOL) continue;
#pragma unroll
            for (int i = 0; i < 4; ++i) {
                int mb = m0 + wm + i * 16 + q * 4;
                float4 bs = *(const float4*)(bias + mb);
                ushort4 u;
                u.x = f2bf_bits(eluf(acc[i][jx][0] + bs.x));
                u.y = f2bf_bits(eluf(acc[i][jx][1] + bs.y));
                u.z = f2bf_bits(eluf(acc[i][jx][2] + bs.z));
                u.w = f2bf_bits(eluf(acc[i][jx][3] + bs.w));
                *(ushort4*)(Sb + (size_t)n * 512 + mb) = u;
            }
        }
    } else {
        // fused post1+post2: out[n] += sum_m w2[m]*elu(y1[m][n])
        float part[4] = {0.0f, 0.0f, 0.0f, 0.0f};
#pragma unroll
        for (int i = 0; i < 4; ++i) {
            int mb = m0 + wm + i * 16 + q * 4;
            float4 bs = *(const float4*)(bias + mb);
            float4 wv = *(const float4*)(w2 + mb);
#pragma unroll
            for (int jx = 0; jx < 4; ++jx) {
                part[jx] += wv.x * eluf(acc[i][jx][0] + bs.x);
                part[jx] += wv.y * eluf(acc[i][jx][1] + bs.y);
                part[jx] += wv.z * eluf(acc[i][jx][2] + bs.z);
                part[jx] += wv.w * eluf(acc[i][jx][3] + bs.w);
            }
        }
#pragma unroll
        for (int jx = 0; jx < 4; ++jx) {
            float v = part[jx];
            v += __shfl_xor(v, 16, 64);
            v += __shfl_xor(v, 32, 64);
            int n = n0 + wn + jx * 16 + r;
            if (q == 0 && n < NCOL) atomicAdd(outp + n, v);
        }
    }
}

// ---------------- out init: out[n] = b_post2 (d_out is re-poisoned each replay) ----------------
__global__ __launch_bounds__(256) void init_out_kernel(
    const float* __restrict__ b2, float* __restrict__ out, int N)
{
    int n = blockIdx.x * 256 + threadIdx.x;
    if (n < N) out[n] = b2[0];
}

extern "C" void kernel_launch(void* const* d_in, const int* in_sizes, int n_in,
                              void* d_out, int out_size, void* d_ws, size_t ws_size,
                              hipStream_t stream)
{
    const float* x      = (const float*)d_in[0];
    const float* w_in   = (const float*)d_in[1];
    const float* b_in   = (const float*)d_in[2];
    const float* w_sig  = (const float*)d_in[3];
    const float* b_sig  = (const float*)d_in[4];
    const float* w_tanh = (const float*)d_in[5];
    const float* b_tanh = (const float*)d_in[6];
    const float* w_skip = (const float*)d_in[7];
    const float* b_skip = (const float*)d_in[8];
    const float* w_res  = (const float*)d_in[9];
    const float* b_res  = (const float*)d_in[10];
    const float* w_post1 = (const float*)d_in[11];
    const float* b_post1 = (const float*)d_in[12];
    const float* w_post2 = (const float*)d_in[13];
    const float* b_post2 = (const float*)d_in[14];
    float* out = (float*)d_out;

    char* ws = (char*)d_ws;
    __hip_bfloat16* hAh = (__hip_bfloat16*)(ws + OFF_HAH);
    __hip_bfloat16* hAl = (__hip_bfloat16*)(ws + OFF_HAL);
    __hip_bfloat16* hBh = (__hip_bfloat16*)(ws + OFF_HBH);
    __hip_bfloat16* hBl = (__hip_bfloat16*)(ws + OFF_HBL);
    __hip_bfloat16* wgh = (__hip_bfloat16*)(ws + OFF_WGH);
    __hip_bfloat16* wgl = (__hip_bfloat16*)(ws + OFF_WGL);
    __hip_bfloat16* wrh = (__hip_bfloat16*)(ws + OFF_WRH);
    __hip_bfloat16* wrl = (__hip_bfloat16*)(ws + OFF_WRL);
    float* bgate = (float*)(ws + OFF_BG);
    __hip_bfloat16* Apack  = (__hip_bfloat16*)(ws + OFF_AP);
    __hip_bfloat16* w1pack = (__hip_bfloat16*)(ws + OFF_W1P);
    float* bsum = (float*)(ws + OFF_BS);
    __hip_bfloat16* Sb = (__hip_bfloat16*)(ws + OFF_SB);
    __hip_bfloat16* Gt = (__hip_bfloat16*)(ws + OFF_GT);

    in_conv_kernel<<<dim3(T_IN / 32, BATCH), 256, 0, stream>>>(x, w_in, b_in, hAh, hAl);
    pack_kernel<<<dim3(512 * 1600 / 256), 256, 0, stream>>>(
        w_skip, b_skip, w_post1, w_sig, w_tanh, w_res, b_sig, b_tanh,
        Apack, w1pack, wgh, wgl, wrh, wrl, bgate, bsum);

    int L = T_IN;
    __hip_bfloat16 *cih = hAh, *cil = hAl, *coh = hBh, *col_ = hBl;
    for (int rep = 0; rep < 5; ++rep) {
        {   // group A: layers rep*10 .. +4, d=1..16 (S=1)
            int out_len = L - 31;
            int n_ut = (out_len + 95) / 96;
            group_kernel<1><<<dim3(BATCH * n_ut), 256, 0, stream>>>(
                cih, cil, coh, col_, Gt, wgh, wrh, wrl, bgate, b_res,
                rep * 10, L, n_ut);
            L = out_len;
            __hip_bfloat16* t1 = cih; cih = coh; coh = t1;
            __hip_bfloat16* t2 = cil; cil = col_; col_ = t2;
        }
        {   // group B: layers rep*10+5 .. +9, d=32..512 (S=32 polyphase)
            int U = (L + 31) / 32;
            int out_u = U - 31; if (out_u < 1) out_u = 1;
            int n_ut = (out_u + 95) / 96;
            group_kernel<32><<<dim3(BATCH * 32 * n_ut), 256, 0, stream>>>(
                cih, cil, coh, col_, Gt, wgh, wrh, wrl, bgate, b_res,
                rep * 10 + 5, L, n_ut);
            L = L - 992;
            __hip_bfloat16* t1 = cih; cih = coh; coh = t1;
            __hip_bfloat16* t2 = cil; cil = col_; col_ = t2;
        }
    }

    // skip GEMM: Sb[n][512] = bf16(elu(Apack(512x1600) * Gt^T + bsum))
    mfma_gemm_kernel<0><<<dim3(400), 512, 0, stream>>>(
        Apack, 1600, Gt, 1600, bsum, (void*)Sb, nullptr, nullptr, 1600);
    // out[n] = b_post2
    init_out_kernel<<<dim3((NCOL + 255) / 256), 256, 0, stream>>>(b_post2, out, NCOL);
    // fused post1+post2: out[n] += sum_m w2[m]*elu(W1*Sb^T + b_post1)
    mfma_gemm_kernel<1><<<dim3(400), 512, 0, stream>>>(
        w1pack, 512, Sb, 512, b_post1, nullptr, w_post2, out, 512);
}